// Round 11
// baseline (410.374 us; speedup 1.0000x reference)
//
#include <hip/hip_runtime.h>

#define N_NODES 50000
#define N_EDGES 800000

typedef __attribute__((ext_vector_type(8))) short short8;
typedef __attribute__((ext_vector_type(4))) short bf16x4;
typedef __attribute__((ext_vector_type(4))) float floatx4;
typedef __attribute__((ext_vector_type(2))) __bf16 bfv2;

__device__ __forceinline__ short f2bf(float f) {
  unsigned int u = __builtin_bit_cast(unsigned int, f);
  unsigned int r = (u + 0x7FFFu + ((u >> 16) & 1u)) >> 16;
  return (short)r;
}
// pack two f32 -> packed bf16 dword via compiler casts (RNE); clang fuses the
// fptrunc pair into the packed HW convert on gfx950 and keeps sched freedom.
__device__ __forceinline__ unsigned int pack2bf(float a, float b) {
  bfv2 v;
  v.x = (__bf16)a;
  v.y = (__bf16)b;
  return __builtin_bit_cast(unsigned int, v);
}
__device__ __forceinline__ float bflo2f(unsigned int u) {
  return __builtin_bit_cast(float, u << 16);
}
__device__ __forceinline__ float bfhi2f(unsigned int u) {
  return __builtin_bit_cast(float, u & 0xFFFF0000u);
}
__device__ __forceinline__ float fsilu(float v) {
  float e = __builtin_amdgcn_exp2f(v * -1.442695041f);
  return v * __builtin_amdgcn_rcpf(1.f + e);
}

// K=16 bf16 MFMA (for the segmented-reduce aggregation)
__device__ __forceinline__ floatx4 mfma16bf16(bf16x4 a, bf16x4 b, floatx4 c) {
#if __has_builtin(__builtin_amdgcn_mfma_f32_16x16x16bf16_1k)
  return __builtin_amdgcn_mfma_f32_16x16x16bf16_1k(a, b, c, 0, 0, 0);
#elif __has_builtin(__builtin_amdgcn_mfma_f32_16x16x16_bf16)
  return __builtin_amdgcn_mfma_f32_16x16x16_bf16(a, b, c, 0, 0, 0);
#else
  floatx4 d;
  asm volatile("v_mfma_f32_16x16x16_bf16 %0, %1, %2, %3"
               : "=&v"(d) : "v"(a), "v"(b), "v"(c));
  return d;
#endif
}

// f32 weights [K,128] -> bf16 MFMA frag order (A-frag of W^T == B-frag of W)
__global__ void prep_weights(const float* __restrict__ eW1, const float* __restrict__ eW2,
                             const float* __restrict__ nW1, const float* __restrict__ nW2,
                             short* __restrict__ W1f, short* __restrict__ W2f,
                             short* __restrict__ N1f, short* __restrict__ N2f) {
  int id = blockIdx.x * 256 + threadIdx.x;   // 0..12287
  const float* src; short* dst; int ch;
  if (id < 4096)       { src = eW1; dst = W1f; ch = id; }
  else if (id < 6144)  { src = eW2; dst = W2f; ch = id - 4096; }
  else if (id < 10240) { src = nW1; dst = N1f; ch = id - 6144; }
  else                 { src = nW2; dst = N2f; ch = id - 10240; }
  int kt = ch >> 9;
  int c  = (ch >> 6) & 7;
  int l  = ch & 63;
  int q = l >> 4, n = l & 15;
  int k0 = kt * 32 + q * 8;
  int col = c * 16 + n;
  short tmp[8];
#pragma unroll
  for (int j = 0; j < 8; ++j) tmp[j] = f2bf(src[(k0 + j) * 128 + col]);
#pragma unroll
  for (int j = 0; j < 8; ++j) dst[ch * 8 + j] = tmp[j];
}

// Per-node layer-1 split: R' = h @ eW1_top + eb1,  S = h @ eW1_bot (both bf16).
// Transposed GEMM, 64 nodes/block, 512 threads.
__global__ void __launch_bounds__(512, 6) prep_hR(
    const float* __restrict__ h, const short* __restrict__ W1f,
    const float* __restrict__ eb1,
    short* __restrict__ Rb, short* __restrict__ Sb) {
  __shared__ __align__(16) short Z[64 * 136];
  const int tid = threadIdx.x;
  const int n0 = blockIdx.x * 64;
#pragma unroll
  for (int i = 0; i < 4; ++i) {
    int id = i * 512 + tid;
    int r = id >> 5, cq = id & 31;
    int rg = n0 + r; if (rg >= N_NODES) rg = N_NODES - 1;
    float4 v = *(const float4*)(h + (size_t)rg * 128 + cq * 4);
    uint2 s;
    s.x = pack2bf(v.x, v.y);
    s.y = pack2bf(v.z, v.w);
    *(uint2*)(Z + r * 136 + cq * 4) = s;
  }
  __syncthreads();
  const int w = tid >> 6, lane = tid & 63, q = lane >> 4, n = lane & 15;
  const int et = w & 3, cg = w >> 2;
  const int erow = et * 16 + n;
  floatx4 accR[4], accS[4];
#pragma unroll
  for (int cc = 0; cc < 4; ++cc) {
    accR[cc] = (floatx4){0.f, 0.f, 0.f, 0.f};
    accS[cc] = (floatx4){0.f, 0.f, 0.f, 0.f};
  }
  const short* Brow = Z + erow * 136 + q * 8;
  const short8* A = (const short8*)W1f;
#pragma unroll
  for (int kt = 0; kt < 4; ++kt) {
    short8 b = *(const short8*)(Brow + kt * 32);
#pragma unroll
    for (int cc = 0; cc < 4; ++cc) {
      short8 aT = A[kt * 512 + (cg * 4 + cc) * 64 + lane];          // top half
      accR[cc] = __builtin_amdgcn_mfma_f32_16x16x32_bf16(aT, b, accR[cc], 0, 0, 0);
      short8 aB = A[(kt + 4) * 512 + (cg * 4 + cc) * 64 + lane];    // bottom half
      accS[cc] = __builtin_amdgcn_mfma_f32_16x16x32_bf16(aB, b, accS[cc], 0, 0, 0);
    }
  }
  const int node = n0 + erow;
  if (node < N_NODES) {
#pragma unroll
    for (int cc = 0; cc < 4; ++cc) {
      int col = (cg * 4 + cc) * 16 + 4 * q;
      const float4 b1 = *(const float4*)(eb1 + col);
      uint2 ur, us;
      ur.x = pack2bf(accR[cc][0] + b1.x, accR[cc][1] + b1.y);
      ur.y = pack2bf(accR[cc][2] + b1.z, accR[cc][3] + b1.w);
      us.x = pack2bf(accS[cc][0], accS[cc][1]);
      us.y = pack2bf(accS[cc][2], accS[cc][3]);
      *(uint2*)(Rb + (size_t)node * 128 + col) = ur;
      *(uint2*)(Sb + (size_t)node * 128 + col) = us;
    }
  }
}

// ---- CSR build: histogram of destination rows; atomic return = edge's rank
__global__ void hist_kernel(const int* __restrict__ idx, int* __restrict__ cnt,
                            int* __restrict__ rank) {
  int gid = blockIdx.x * 256 + threadIdx.x;
  rank[gid] = atomicAdd(&cnt[idx[gid]], 1);
}

// two-level exclusive scan of cnt[50000] -> ctmp
__global__ void scan1(const int* __restrict__ cnt, int* __restrict__ bsum) {
  const int t = threadIdx.x;
  int i = blockIdx.x * 512 + t;
  int v = (i < N_NODES) ? cnt[i] : 0;
#pragma unroll
  for (int o = 1; o < 64; o <<= 1) v += __shfl_xor(v, o, 64);
  __shared__ int ws_[8];
  if ((t & 63) == 0) ws_[t >> 6] = v;
  __syncthreads();
  if (t == 0) {
    int s = 0;
#pragma unroll
    for (int k = 0; k < 8; ++k) s += ws_[k];
    bsum[blockIdx.x] = s;
  }
}

__global__ void scan2(const int* __restrict__ bsum, int* __restrict__ boff) {
  const int t = threadIdx.x;   // 128 threads
  int v = (t < 98) ? bsum[t] : 0;
  int incl = v;
  const int lane = t & 63;
#pragma unroll
  for (int o = 1; o < 64; o <<= 1) {
    int tmp = __shfl_up(incl, o, 64);
    if (lane >= o) incl += tmp;
  }
  __shared__ int s0;
  if (t == 63) s0 = incl;
  __syncthreads();
  if (t >= 64) incl += s0;
  boff[t] = incl - v;
}

__global__ void scan3(const int* __restrict__ cnt, const int* __restrict__ boff,
                      int* __restrict__ ctmp) {
  const int t = threadIdx.x;
  const int i = blockIdx.x * 512 + t;
  int v = (i < N_NODES) ? cnt[i] : 0;
  int incl = v;
  const int lane = t & 63;
#pragma unroll
  for (int o = 1; o < 64; o <<= 1) {
    int tmp = __shfl_up(incl, o, 64);
    if (lane >= o) incl += tmp;
  }
  __shared__ int wsum[8];
  if (lane == 63) wsum[t >> 6] = incl;
  __syncthreads();
  if (t == 0) {
    int run = 0;
#pragma unroll
    for (int k = 0; k < 8; ++k) { int x = wsum[k]; wsum[k] = run; run += x; }
  }
  __syncthreads();
  if (i < N_NODES) ctmp[i] = incl - v + wsum[t >> 6] + boff[blockIdx.x];
}

// place edges into sorted order: p = row_base + precomputed rank (NO atomics)
__global__ void place_kernel(const int* __restrict__ idx, const int* __restrict__ ctmp,
                             const int* __restrict__ rank, int2* __restrict__ sedge) {
  int gid = blockIdx.x * 256 + threadIdx.x;
  int r = idx[gid];
  int c = idx[N_EDGES + gid];
  int p = ctmp[r] + rank[gid];
  sedge[p] = make_int2(r, c);
}

// ---- edge-kernel building blocks (inlined twice for the 2-tile pipeline) ----
__device__ __forceinline__ void edge_l1(const uint4* gr, const uint4* gs, short8* a) {
#pragma unroll
  for (int kt = 0; kt < 4; ++kt) {
    uint4 ur = gr[kt];
    uint4 us = gs[kt];
    float v0 = bflo2f(ur.x) + bflo2f(us.x);
    float v1 = bfhi2f(ur.x) + bfhi2f(us.x);
    float v2 = bflo2f(ur.y) + bflo2f(us.y);
    float v3 = bfhi2f(ur.y) + bfhi2f(us.y);
    float v4 = bflo2f(ur.z) + bflo2f(us.z);
    float v5 = bfhi2f(ur.z) + bfhi2f(us.z);
    float v6 = bflo2f(ur.w) + bflo2f(us.w);
    float v7 = bfhi2f(ur.w) + bfhi2f(us.w);
    uint4 pa;
    pa.x = pack2bf(fsilu(v0), fsilu(v1));
    pa.y = pack2bf(fsilu(v2), fsilu(v3));
    pa.z = pack2bf(fsilu(v4), fsilu(v5));
    pa.w = pack2bf(fsilu(v6), fsilu(v7));
    a[kt] = __builtin_bit_cast(short8, pa);
  }
}

__device__ __forceinline__ void edge_mm(const short8* a, const short8* B, int lane,
                                        floatx4* acc2) {
#pragma unroll
  for (int cc = 0; cc < 8; ++cc) acc2[cc] = (floatx4){0.f, 0.f, 0.f, 0.f};
#pragma unroll
  for (int kt = 0; kt < 4; ++kt) {
#pragma unroll
    for (int cc = 0; cc < 8; ++cc) {
      short8 b = B[kt * 512 + cc * 64 + lane];
      acc2[cc] = __builtin_amdgcn_mfma_f32_16x16x32_bf16(a[kt], b, acc2[cc], 0, 0, 0);
    }
  }
}

// post: bias+silu, att dot + width-16 reduce, run machinery, indicator agg-MFMA.
// Produces flush packet (fire, basep, 16 packed dwords); does NOT issue atomics.
__device__ __forceinline__ void edge_post(
    const floatx4* acc2, int myrow, const float* bia_n, const float* aw_n,
    float ab0, int w, int q, int n, int* runrowS,
    unsigned short* __restrict__ agg,
    bool& fire, unsigned short*& basep, unsigned int* uo) {
  float p0 = 0.f, p1 = 0.f, p2 = 0.f, p3 = 0.f;
  uint2 af[8];
#pragma unroll
  for (int cc = 0; cc < 8; ++cc) {
    float bia = bia_n[cc];
    float awv = aw_n[cc];
    float v0 = fsilu(acc2[cc][0] + bia);
    float v1 = fsilu(acc2[cc][1] + bia);
    float v2 = fsilu(acc2[cc][2] + bia);
    float v3 = fsilu(acc2[cc][3] + bia);
    p0 += v0 * awv; p1 += v1 * awv; p2 += v2 * awv; p3 += v3 * awv;
    af[cc].x = pack2bf(v0, v1);
    af[cc].y = pack2bf(v2, v3);
  }
#pragma unroll
  for (int d = 1; d < 16; d <<= 1) {
    p0 += __shfl_xor(p0, d, 16);
    p1 += __shfl_xor(p1, d, 16);
    p2 += __shfl_xor(p2, d, 16);
    p3 += __shfl_xor(p3, d, 16);
  }
  int rprev = __shfl_up(myrow, 1, 16);
  bool head = (n == 0) || (myrow != rprev);
  unsigned long long bal = __ballot(head);
  unsigned int mask16 = (unsigned int)(bal >> (q * 16)) & 0xFFFFu;
  int nRuns = __popc(mask16);
  if (head && q == 0) {
    int ridn = __popc(mask16 & ((2u << n) - 1u)) - 1;
    runrowS[w * 16 + ridn] = myrow;
  }
  asm volatile("s_waitcnt lgkmcnt(0)" ::: "memory");   // same-wave LDS RAW
  __builtin_amdgcn_sched_barrier(0);
  int rowdst = runrowS[w * 16 + n];
  int rid4[4];
#pragma unroll
  for (int j = 0; j < 4; ++j)
    rid4[j] = __popc(mask16 & ((2u << (4 * q + j)) - 1u)) - 1;
  float att[4];
  {
    float pv[4] = {p0, p1, p2, p3};
#pragma unroll
    for (int j = 0; j < 4; ++j) {
      float s = pv[j] + ab0;
      att[j] = 0.01f * __builtin_amdgcn_rcpf(1.f + __builtin_amdgcn_exp2f(-1.442695041f * s));
    }
  }
  uint2 iu;
  iu.x = pack2bf(rid4[0] == n ? att[0] : 0.f, rid4[1] == n ? att[1] : 0.f);
  iu.y = pack2bf(rid4[2] == n ? att[2] : 0.f, rid4[3] == n ? att[3] : 0.f);
  bf16x4 ind = __builtin_bit_cast(bf16x4, iu);
  const floatx4 zero4 = (floatx4){0.f, 0.f, 0.f, 0.f};
#pragma unroll
  for (int cc = 0; cc < 8; ++cc) {
    floatx4 ag = mfma16bf16(__builtin_bit_cast(bf16x4, af[cc]), ind, zero4);
    uo[2 * cc]     = pack2bf(ag[0], ag[1]);
    uo[2 * cc + 1] = pack2bf(ag[2], ag[3]);
  }
  fire = (n < nRuns);
  basep = agg + (size_t)rowdst * 128;
}

__device__ __forceinline__ void edge_flush(bool fire, unsigned short* basep,
                                           const unsigned int* uo, int q) {
  if (fire) {
#pragma unroll
    for (int cc = 0; cc < 8; ++cc) {
      int colb = cc * 16 + 4 * q;
      asm volatile("global_atomic_pk_add_bf16 %0, %1, off"
                   :: "v"(basep + colb), "v"(uo[2 * cc]) : "memory");
      asm volatile("global_atomic_pk_add_bf16 %0, %1, off"
                   :: "v"(basep + colb + 2), "v"(uo[2 * cc + 1]) : "memory");
    }
  }
}

// Edge kernel: 2 ADJACENT 16-edge tiles per wave, software-pipelined, zero
// barriers. Block b owns tile-groups 2b,2b+1 (contiguous -> identical cache
// window to one-tile dispatch; rounds 6/8 lesson: grid-stride reordering blew
// FETCH 84.7->924 MB). All 16 gathers (A+B) issue up front; tile A computes
// while B's gathers fly. A's UNTRACKED asm atomics are deferred until after
// B's layer-1 consumed the last tracked load, so no compiler vmcnt wait ever
// has to drain an atomic (rounds 6/8 second lesson).
__global__ void __launch_bounds__(256, 4) edge_kernel(
    const short* __restrict__ Rb, const short* __restrict__ Sb,
    const int2* __restrict__ sedge, const short* __restrict__ W2f,
    const float* __restrict__ eb2, const float* __restrict__ aW,
    const float* __restrict__ ab, unsigned short* __restrict__ agg) {
  __shared__ int runrowS[64];     // 4 waves * 16 runs (reused per tile, intra-wave)
  const int tid = threadIdx.x;
  const int w = tid >> 6, lane = tid & 63, q = lane >> 4, n = lane & 15;
  const int eA = blockIdx.x * 128 + w * 16;   // tile A edges
  const int eB = eA + 64;                     // tile B edges (adjacent group)

  // loop-invariant per-lane weights (loaded once per block)
  const float ab0 = ab[0];
  float bia_n[8], aw_n[8];
#pragma unroll
  for (int cc = 0; cc < 8; ++cc) {
    bia_n[cc] = eb2[cc * 16 + n];
    aw_n[cc]  = aW[cc * 16 + n];
  }

  const int2 edA = sedge[eA + n];
  const int2 edB = sedge[eB + n];
  uint4 grA[4], gsA[4], grB[4], gsB[4];
  {
    const short* RrowA = Rb + (size_t)edA.x * 128 + q * 8;
    const short* SrowA = Sb + (size_t)edA.y * 128 + q * 8;
    const short* RrowB = Rb + (size_t)edB.x * 128 + q * 8;
    const short* SrowB = Sb + (size_t)edB.y * 128 + q * 8;
#pragma unroll
    for (int kt = 0; kt < 4; ++kt) {
      grA[kt] = *(const uint4*)(RrowA + kt * 32);
      gsA[kt] = *(const uint4*)(SrowA + kt * 32);
    }
#pragma unroll
    for (int kt = 0; kt < 4; ++kt) {
      grB[kt] = *(const uint4*)(RrowB + kt * 32);
      gsB[kt] = *(const uint4*)(SrowB + kt * 32);
    }
  }

  // ---- tile A: layer1 (waits A loads only), MFMA, post
  short8 aA[4];
  edge_l1(grA, gsA, aA);
  floatx4 accA[8];
  edge_mm(aA, (const short8*)W2f, lane, accA);
  bool fireA; unsigned short* basepA; unsigned int uA[16];
  edge_post(accA, edA.x, bia_n, aw_n, ab0, w, q, n, runrowS, agg, fireA, basepA, uA);

  // ---- tile B layer-1 consumes the last tracked loads BEFORE any atomic
  short8 aB[4];
  edge_l1(grB, gsB, aB);
  edge_flush(fireA, basepA, uA, q);   // A's atomics: no tracked loads remain
  floatx4 accB[8];
  edge_mm(aB, (const short8*)W2f, lane, accB);
  bool fireB; unsigned short* basepB; unsigned int uB[16];
  edge_post(accB, edB.x, bia_n, aw_n, ab0, w, q, n, runrowS, agg, fireB, basepB, uB);
  edge_flush(fireB, basepB, uB, q);

  asm volatile("s_waitcnt vmcnt(0)" ::: "memory");   // drain untracked asm atomics
}

// Node kernel (transposed, 512 threads): 64 nodes/block, 8 waves.
__global__ void __launch_bounds__(512, 6) node_kernel(
    const float* __restrict__ h, const short* __restrict__ agg,
    const short* __restrict__ N1f, const short* __restrict__ N2f,
    const float* __restrict__ nb1, const float* __restrict__ nb2,
    float* __restrict__ out) {
  __shared__ __align__(16) short Smem[16896];   // Z[64][264] overlaid by M1[64][136]
  const int tid = threadIdx.x;
  const int n0 = blockIdx.x * 64;
#pragma unroll
  for (int i = 0; i < 4; ++i) {
    int id = i * 512 + tid;
    int r = id >> 5, ch = id & 31;
    int rg = n0 + r;
    if (rg >= N_NODES) rg = N_NODES - 1;
    if (ch < 16) {
      const float* hp = h + (size_t)rg * 128 + ch * 8;
      float4 a = *(const float4*)hp;
      float4 b = *(const float4*)(hp + 4);
      uint4 sv;
      sv.x = pack2bf(a.x, a.y);
      sv.y = pack2bf(a.z, a.w);
      sv.z = pack2bf(b.x, b.y);
      sv.w = pack2bf(b.z, b.w);
      *(uint4*)(Smem + r * 264 + ch * 8) = sv;
    } else {
      *(uint4*)(Smem + r * 264 + ch * 8) =
          *(const uint4*)(agg + (size_t)rg * 128 + (ch - 16) * 8);
    }
  }
  __syncthreads();
  const int w = tid >> 6, lane = tid & 63, q = lane >> 4, n = lane & 15;
  const int et = w & 3, cg = w >> 2;
  const int erow = et * 16 + n;

  floatx4 acc[4];
#pragma unroll
  for (int cc = 0; cc < 4; ++cc) acc[cc] = (floatx4){0.f, 0.f, 0.f, 0.f};
  {
    const short* Brow = Smem + erow * 264 + q * 8;
    const short8* A = (const short8*)N1f;
#pragma unroll
    for (int kt = 0; kt < 8; ++kt) {
      short8 b = *(const short8*)(Brow + kt * 32);
#pragma unroll
      for (int cc = 0; cc < 4; ++cc) {
        short8 a = A[kt * 512 + (cg * 4 + cc) * 64 + lane];
        acc[cc] = __builtin_amdgcn_mfma_f32_16x16x32_bf16(a, b, acc[cc], 0, 0, 0);
      }
    }
  }
  unsigned int m1p[4][2];
#pragma unroll
  for (int cc = 0; cc < 4; ++cc) {
    int ct = cg * 4 + cc;
    const float4 b1 = *(const float4*)(nb1 + ct * 16 + 4 * q);
    m1p[cc][0] = pack2bf(fsilu(acc[cc][0] + b1.x), fsilu(acc[cc][1] + b1.y));
    m1p[cc][1] = pack2bf(fsilu(acc[cc][2] + b1.z), fsilu(acc[cc][3] + b1.w));
  }
  __syncthreads();
#pragma unroll
  for (int cc = 0; cc < 4; ++cc) {
    int ct = cg * 4 + cc;
    *(uint2*)(Smem + erow * 136 + ct * 16 + 4 * q) = *(uint2*)m1p[cc];
  }
  __syncthreads();

  floatx4 acc2[4];
#pragma unroll
  for (int cc = 0; cc < 4; ++cc) acc2[cc] = (floatx4){0.f, 0.f, 0.f, 0.f};
  {
    const short* Brow = Smem + erow * 136 + q * 8;
    const short8* A = (const short8*)N2f;
#pragma unroll
    for (int kt = 0; kt < 4; ++kt) {
      short8 b = *(const short8*)(Brow + kt * 32);
#pragma unroll
      for (int cc = 0; cc < 4; ++cc) {
        short8 a = A[kt * 512 + (cg * 4 + cc) * 64 + lane];
        acc2[cc] = __builtin_amdgcn_mfma_f32_16x16x32_bf16(a, b, acc2[cc], 0, 0, 0);
      }
    }
  }
  const int node = n0 + erow;
  if (node < N_NODES) {
#pragma unroll
    for (int cc = 0; cc < 4; ++cc) {
      int col = (cg * 4 + cc) * 16 + 4 * q;
      const float4 b2 = *(const float4*)(nb2 + col);
      const float4 hr = *(const float4*)(h + (size_t)node * 128 + col);
      float4 o;
      o.x = acc2[cc][0] + b2.x + hr.x;
      o.y = acc2[cc][1] + b2.y + hr.y;
      o.z = acc2[cc][2] + b2.z + hr.z;
      o.w = acc2[cc][3] + b2.w + hr.w;
      *(float4*)(out + (size_t)node * 128 + col) = o;
    }
  }
}

extern "C" void kernel_launch(void* const* d_in, const int* in_sizes, int n_in,
                              void* d_out, int out_size, void* d_ws, size_t ws_size,
                              hipStream_t stream) {
  (void)in_sizes; (void)n_in; (void)out_size; (void)ws_size;
  const float* h   = (const float*)d_in[0];
  const int*   idx = (const int*)d_in[1];
  const float* eW1 = (const float*)d_in[2];
  const float* eb1 = (const float*)d_in[3];
  const float* eW2 = (const float*)d_in[4];
  const float* eb2 = (const float*)d_in[5];
  const float* aW  = (const float*)d_in[6];
  const float* ab  = (const float*)d_in[7];
  const float* nW1 = (const float*)d_in[8];
  const float* nb1 = (const float*)d_in[9];
  const float* nW2 = (const float*)d_in[10];
  const float* nb2 = (const float*)d_in[11];
  float* out = (float*)d_out;

  // ws layout
  char* wp = (char*)d_ws;
  unsigned short* agg = (unsigned short*)wp;  wp += (size_t)N_NODES * 128 * 2;  // 12.8 MB
  short* Rb  = (short*)wp;                    wp += (size_t)N_NODES * 128 * 2;  // 12.8 MB
  short* Sb  = (short*)wp;                    wp += (size_t)N_NODES * 128 * 2;  // 12.8 MB
  short* W1f = (short*)wp;                    wp += 32768 * 2;
  short* W2f = (short*)wp;                    wp += 16384 * 2;
  short* N1f = (short*)wp;                    wp += 32768 * 2;
  short* N2f = (short*)wp;                    wp += 16384 * 2;
  int* cnt  = (int*)wp;                       wp += N_NODES * 4;
  int* ctmp = (int*)wp;                       wp += N_NODES * 4;
  int* rank = (int*)wp;                       wp += (size_t)N_EDGES * 4;
  int2* sedge = (int2*)wp;                    wp += (size_t)N_EDGES * 8;
  int* bsum = (int*)wp;                       wp += 128 * 4;
  int* boff = (int*)wp;                       wp += 128 * 4;

  hipMemsetAsync(agg, 0, (size_t)N_NODES * 128 * 2, stream);
  hipMemsetAsync(cnt, 0, N_NODES * 4, stream);
  prep_weights<<<48, 256, 0, stream>>>(eW1, eW2, nW1, nW2, W1f, W2f, N1f, N2f);
  prep_hR<<<(N_NODES + 63) / 64, 512, 0, stream>>>(h, W1f, eb1, Rb, Sb);
  hist_kernel<<<N_EDGES / 256, 256, 0, stream>>>(idx, cnt, rank);
  scan1<<<98, 512, 0, stream>>>(cnt, bsum);
  scan2<<<1, 128, 0, stream>>>(bsum, boff);
  scan3<<<98, 512, 0, stream>>>(cnt, boff, ctmp);
  place_kernel<<<N_EDGES / 256, 256, 0, stream>>>(idx, ctmp, rank, sedge);
  edge_kernel<<<N_EDGES / 128, 256, 0, stream>>>(Rb, Sb, sedge, W2f,
                                                 eb2, aW, ab, agg);
  node_kernel<<<(N_NODES + 63) / 64, 512, 0, stream>>>(h, (const short*)agg,
                                                       N1f, N2f, nb1, nb2, out);
}

// Round 12
// 358.740 us; speedup vs baseline: 1.1439x; 1.1439x over previous
//
#include <hip/hip_runtime.h>

#define N_NODES 50000
#define N_EDGES 800000

typedef __attribute__((ext_vector_type(8))) short short8;
typedef __attribute__((ext_vector_type(4))) short bf16x4;
typedef __attribute__((ext_vector_type(4))) float floatx4;
typedef __attribute__((ext_vector_type(2))) __bf16 bfv2;

__device__ __forceinline__ short f2bf(float f) {
  unsigned int u = __builtin_bit_cast(unsigned int, f);
  unsigned int r = (u + 0x7FFFu + ((u >> 16) & 1u)) >> 16;
  return (short)r;
}
// pack two f32 -> packed bf16 dword via compiler casts (RNE); clang fuses the
// fptrunc pair into the packed HW convert on gfx950 and keeps sched freedom.
__device__ __forceinline__ unsigned int pack2bf(float a, float b) {
  bfv2 v;
  v.x = (__bf16)a;
  v.y = (__bf16)b;
  return __builtin_bit_cast(unsigned int, v);
}
__device__ __forceinline__ float bflo2f(unsigned int u) {
  return __builtin_bit_cast(float, u << 16);
}
__device__ __forceinline__ float bfhi2f(unsigned int u) {
  return __builtin_bit_cast(float, u & 0xFFFF0000u);
}
__device__ __forceinline__ float fsilu(float v) {
  float e = __builtin_amdgcn_exp2f(v * -1.442695041f);
  return v * __builtin_amdgcn_rcpf(1.f + e);
}

// K=16 bf16 MFMA (for the segmented-reduce aggregation)
__device__ __forceinline__ floatx4 mfma16bf16(bf16x4 a, bf16x4 b, floatx4 c) {
#if __has_builtin(__builtin_amdgcn_mfma_f32_16x16x16bf16_1k)
  return __builtin_amdgcn_mfma_f32_16x16x16bf16_1k(a, b, c, 0, 0, 0);
#elif __has_builtin(__builtin_amdgcn_mfma_f32_16x16x16_bf16)
  return __builtin_amdgcn_mfma_f32_16x16x16_bf16(a, b, c, 0, 0, 0);
#else
  floatx4 d;
  asm volatile("v_mfma_f32_16x16x16_bf16 %0, %1, %2, %3"
               : "=&v"(d) : "v"(a), "v"(b), "v"(c));
  return d;
#endif
}

// f32 weights [K,128] -> bf16 MFMA frag order (A-frag of W^T == B-frag of W)
__global__ void prep_weights(const float* __restrict__ eW1, const float* __restrict__ eW2,
                             const float* __restrict__ nW1, const float* __restrict__ nW2,
                             short* __restrict__ W1f, short* __restrict__ W2f,
                             short* __restrict__ N1f, short* __restrict__ N2f) {
  int id = blockIdx.x * 256 + threadIdx.x;   // 0..12287
  const float* src; short* dst; int ch;
  if (id < 4096)       { src = eW1; dst = W1f; ch = id; }
  else if (id < 6144)  { src = eW2; dst = W2f; ch = id - 4096; }
  else if (id < 10240) { src = nW1; dst = N1f; ch = id - 6144; }
  else                 { src = nW2; dst = N2f; ch = id - 10240; }
  int kt = ch >> 9;
  int c  = (ch >> 6) & 7;
  int l  = ch & 63;
  int q = l >> 4, n = l & 15;
  int k0 = kt * 32 + q * 8;
  int col = c * 16 + n;
  short tmp[8];
#pragma unroll
  for (int j = 0; j < 8; ++j) tmp[j] = f2bf(src[(k0 + j) * 128 + col]);
#pragma unroll
  for (int j = 0; j < 8; ++j) dst[ch * 8 + j] = tmp[j];
}

// Per-node layer-1 split: R' = h @ eW1_top + eb1,  S = h @ eW1_bot (both bf16).
// Transposed GEMM, 64 nodes/block, 512 threads.
__global__ void __launch_bounds__(512, 6) prep_hR(
    const float* __restrict__ h, const short* __restrict__ W1f,
    const float* __restrict__ eb1,
    short* __restrict__ Rb, short* __restrict__ Sb) {
  __shared__ __align__(16) short Z[64 * 136];
  const int tid = threadIdx.x;
  const int n0 = blockIdx.x * 64;
#pragma unroll
  for (int i = 0; i < 4; ++i) {
    int id = i * 512 + tid;
    int r = id >> 5, cq = id & 31;
    int rg = n0 + r; if (rg >= N_NODES) rg = N_NODES - 1;
    float4 v = *(const float4*)(h + (size_t)rg * 128 + cq * 4);
    uint2 s;
    s.x = pack2bf(v.x, v.y);
    s.y = pack2bf(v.z, v.w);
    *(uint2*)(Z + r * 136 + cq * 4) = s;
  }
  __syncthreads();
  const int w = tid >> 6, lane = tid & 63, q = lane >> 4, n = lane & 15;
  const int et = w & 3, cg = w >> 2;
  const int erow = et * 16 + n;
  floatx4 accR[4], accS[4];
#pragma unroll
  for (int cc = 0; cc < 4; ++cc) {
    accR[cc] = (floatx4){0.f, 0.f, 0.f, 0.f};
    accS[cc] = (floatx4){0.f, 0.f, 0.f, 0.f};
  }
  const short* Brow = Z + erow * 136 + q * 8;
  const short8* A = (const short8*)W1f;
#pragma unroll
  for (int kt = 0; kt < 4; ++kt) {
    short8 b = *(const short8*)(Brow + kt * 32);
#pragma unroll
    for (int cc = 0; cc < 4; ++cc) {
      short8 aT = A[kt * 512 + (cg * 4 + cc) * 64 + lane];          // top half
      accR[cc] = __builtin_amdgcn_mfma_f32_16x16x32_bf16(aT, b, accR[cc], 0, 0, 0);
      short8 aB = A[(kt + 4) * 512 + (cg * 4 + cc) * 64 + lane];    // bottom half
      accS[cc] = __builtin_amdgcn_mfma_f32_16x16x32_bf16(aB, b, accS[cc], 0, 0, 0);
    }
  }
  const int node = n0 + erow;
  if (node < N_NODES) {
#pragma unroll
    for (int cc = 0; cc < 4; ++cc) {
      int col = (cg * 4 + cc) * 16 + 4 * q;
      const float4 b1 = *(const float4*)(eb1 + col);
      uint2 ur, us;
      ur.x = pack2bf(accR[cc][0] + b1.x, accR[cc][1] + b1.y);
      ur.y = pack2bf(accR[cc][2] + b1.z, accR[cc][3] + b1.w);
      us.x = pack2bf(accS[cc][0], accS[cc][1]);
      us.y = pack2bf(accS[cc][2], accS[cc][3]);
      *(uint2*)(Rb + (size_t)node * 128 + col) = ur;
      *(uint2*)(Sb + (size_t)node * 128 + col) = us;
    }
  }
}

// ---- CSR build: histogram of destination rows; atomic return = edge's rank
__global__ void hist_kernel(const int* __restrict__ idx, int* __restrict__ cnt,
                            int* __restrict__ rank) {
  int gid = blockIdx.x * 256 + threadIdx.x;
  rank[gid] = atomicAdd(&cnt[idx[gid]], 1);
}

// two-level exclusive scan of cnt[50000] -> ctmp
__global__ void scan1(const int* __restrict__ cnt, int* __restrict__ bsum) {
  const int t = threadIdx.x;
  int i = blockIdx.x * 512 + t;
  int v = (i < N_NODES) ? cnt[i] : 0;
#pragma unroll
  for (int o = 1; o < 64; o <<= 1) v += __shfl_xor(v, o, 64);
  __shared__ int ws_[8];
  if ((t & 63) == 0) ws_[t >> 6] = v;
  __syncthreads();
  if (t == 0) {
    int s = 0;
#pragma unroll
    for (int k = 0; k < 8; ++k) s += ws_[k];
    bsum[blockIdx.x] = s;
  }
}

__global__ void scan2(const int* __restrict__ bsum, int* __restrict__ boff) {
  const int t = threadIdx.x;   // 128 threads
  int v = (t < 98) ? bsum[t] : 0;
  int incl = v;
  const int lane = t & 63;
#pragma unroll
  for (int o = 1; o < 64; o <<= 1) {
    int tmp = __shfl_up(incl, o, 64);
    if (lane >= o) incl += tmp;
  }
  __shared__ int s0;
  if (t == 63) s0 = incl;
  __syncthreads();
  if (t >= 64) incl += s0;
  boff[t] = incl - v;
}

__global__ void scan3(const int* __restrict__ cnt, const int* __restrict__ boff,
                      int* __restrict__ ctmp) {
  const int t = threadIdx.x;
  const int i = blockIdx.x * 512 + t;
  int v = (i < N_NODES) ? cnt[i] : 0;
  int incl = v;
  const int lane = t & 63;
#pragma unroll
  for (int o = 1; o < 64; o <<= 1) {
    int tmp = __shfl_up(incl, o, 64);
    if (lane >= o) incl += tmp;
  }
  __shared__ int wsum[8];
  if (lane == 63) wsum[t >> 6] = incl;
  __syncthreads();
  if (t == 0) {
    int run = 0;
#pragma unroll
    for (int k = 0; k < 8; ++k) { int x = wsum[k]; wsum[k] = run; run += x; }
  }
  __syncthreads();
  if (i < N_NODES) ctmp[i] = incl - v + wsum[t >> 6] + boff[blockIdx.x];
}

// place edges into sorted order: p = row_base + precomputed rank (NO atomics)
__global__ void place_kernel(const int* __restrict__ idx, const int* __restrict__ ctmp,
                             const int* __restrict__ rank, int2* __restrict__ sedge) {
  int gid = blockIdx.x * 256 + threadIdx.x;
  int r = idx[gid];
  int c = idx[N_EDGES + gid];
  int p = ctmp[r] + rank[gid];
  sedge[p] = make_int2(r, c);
}

// Edge kernel: wave-autonomous, ZERO barriers, 512 threads = 8 INDEPENDENT
// waves (TLP instead of ILP: rounds 6/8/11 showed multi-tile-per-wave live
// state spills to scratch -> FETCH/WRITE blowup; more resident waves is the
// spill-free way to fill the ~37% idle-issue gap + halve block churn).
// Each wave owns one 16-edge sorted tile and all 128 channels. Lane (q,n):
//   layer-1: m1[edge n][32kt+8q+j] = silu(R[row_n]+S[col_n]) into A-frags.
//   layer-2: D[edge 4q+j][ch ct*16+n] via 32 MFMAs (a=M1 frag, b=W2f frag).
//   att: dot over 128 ch completes with in-wave width-16 shfl_xor reduce.
//   agg: 16x16x16 MFMA, indicator B[k=edge][col=run]=att*(rid==run);
//        lane(q,n) = run n, channels ct*16+4q..+3 -> L2-side pk asm atomics.
__global__ void __launch_bounds__(512, 6) edge_kernel(
    const short* __restrict__ Rb, const short* __restrict__ Sb,
    const int2* __restrict__ sedge, const short* __restrict__ W2f,
    const float* __restrict__ eb2, const float* __restrict__ aW,
    const float* __restrict__ ab, unsigned short* __restrict__ agg) {
  __shared__ int runrowS[128];    // 8 waves * 16 runs
  const int tid = threadIdx.x;
  const int w = tid >> 6, lane = tid & 63, q = lane >> 4, n = lane & 15;
  const int e16 = blockIdx.x * 128 + w * 16;
  const int2 ed = sedge[e16 + n];
  const int myrow = ed.x;

  // ---- layer 1: m1 = silu(R'[row]+S[col]) straight into A-frags
  const short* Rrow = Rb + (size_t)myrow * 128 + q * 8;
  const short* Srow = Sb + (size_t)ed.y * 128 + q * 8;
  short8 a[4];
#pragma unroll
  for (int kt = 0; kt < 4; ++kt) {
    uint4 ur = *(const uint4*)(Rrow + kt * 32);
    uint4 us = *(const uint4*)(Srow + kt * 32);
    float v0 = bflo2f(ur.x) + bflo2f(us.x);
    float v1 = bfhi2f(ur.x) + bfhi2f(us.x);
    float v2 = bflo2f(ur.y) + bflo2f(us.y);
    float v3 = bfhi2f(ur.y) + bfhi2f(us.y);
    float v4 = bflo2f(ur.z) + bflo2f(us.z);
    float v5 = bfhi2f(ur.z) + bfhi2f(us.z);
    float v6 = bflo2f(ur.w) + bflo2f(us.w);
    float v7 = bfhi2f(ur.w) + bfhi2f(us.w);
    uint4 pa;
    pa.x = pack2bf(fsilu(v0), fsilu(v1));
    pa.y = pack2bf(fsilu(v2), fsilu(v3));
    pa.z = pack2bf(fsilu(v4), fsilu(v5));
    pa.w = pack2bf(fsilu(v6), fsilu(v7));
    a[kt] = __builtin_bit_cast(short8, pa);
  }

  // ---- layer 2: D[edge, ch] = M1 @ W2 over all 8 channel tiles
  floatx4 acc2[8];
#pragma unroll
  for (int cc = 0; cc < 8; ++cc) acc2[cc] = (floatx4){0.f, 0.f, 0.f, 0.f};
  {
    const short8* B = (const short8*)W2f;
#pragma unroll
    for (int kt = 0; kt < 4; ++kt) {
#pragma unroll
      for (int cc = 0; cc < 8; ++cc) {
        short8 b = B[kt * 512 + cc * 64 + lane];
        acc2[cc] = __builtin_amdgcn_mfma_f32_16x16x32_bf16(a[kt], b, acc2[cc], 0, 0, 0);
      }
    }
  }

  // ---- bias + silu + att partial dot; pack sil as A-frags (P^T) for agg MFMA
  float p0 = 0.f, p1 = 0.f, p2 = 0.f, p3 = 0.f;
  uint2 af[8];
#pragma unroll
  for (int cc = 0; cc < 8; ++cc) {
    float bia = eb2[cc * 16 + n];
    float awv = aW[cc * 16 + n];
    float v0 = fsilu(acc2[cc][0] + bia);
    float v1 = fsilu(acc2[cc][1] + bia);
    float v2 = fsilu(acc2[cc][2] + bia);
    float v3 = fsilu(acc2[cc][3] + bia);
    p0 += v0 * awv; p1 += v1 * awv; p2 += v2 * awv; p3 += v3 * awv;
    af[cc].x = pack2bf(v0, v1);
    af[cc].y = pack2bf(v2, v3);
  }
  // complete the att dot across the 16 channel lanes (n) of this q-group
#pragma unroll
  for (int d = 1; d < 16; d <<= 1) {
    p0 += __shfl_xor(p0, d, 16);
    p1 += __shfl_xor(p1, d, 16);
    p2 += __shfl_xor(p2, d, 16);
    p3 += __shfl_xor(p3, d, 16);
  }

  // ---- run/head machinery (all intra-wave; rows live in registers)
  int rprev = __shfl_up(myrow, 1, 16);
  bool head = (n == 0) || (myrow != rprev);
  unsigned long long bal = __ballot(head);
  unsigned int mask16 = (unsigned int)(bal >> (q * 16)) & 0xFFFFu;
  int nRuns = __popc(mask16);
  if (head && q == 0) {
    int ridn = __popc(mask16 & ((2u << n) - 1u)) - 1;
    runrowS[w * 16 + ridn] = myrow;
  }
  asm volatile("s_waitcnt lgkmcnt(0)" ::: "memory");   // same-wave LDS RAW
  __builtin_amdgcn_sched_barrier(0);
  int rowdst = runrowS[w * 16 + n];                    // row of run n (if n<nRuns)
  int rid4[4];
#pragma unroll
  for (int j = 0; j < 4; ++j)
    rid4[j] = __popc(mask16 & ((2u << (4 * q + j)) - 1u)) - 1;

  // ---- att per edge 4q+j; indicator B-frag with att folded in
  const float ab0 = ab[0];
  float att[4];
  {
    float pv[4] = {p0, p1, p2, p3};
#pragma unroll
    for (int j = 0; j < 4; ++j) {
      float s = pv[j] + ab0;
      att[j] = 0.01f * __builtin_amdgcn_rcpf(1.f + __builtin_amdgcn_exp2f(-1.442695041f * s));
    }
  }
  uint2 iu;
  iu.x = pack2bf(rid4[0] == n ? att[0] : 0.f, rid4[1] == n ? att[1] : 0.f);
  iu.y = pack2bf(rid4[2] == n ? att[2] : 0.f, rid4[3] == n ? att[3] : 0.f);
  bf16x4 ind = __builtin_bit_cast(bf16x4, iu);

  // ---- aggregation MFMAs: ag[cc] = P_cc^T * Ind
  const floatx4 zero4 = (floatx4){0.f, 0.f, 0.f, 0.f};
  floatx4 ag[8];
#pragma unroll
  for (int cc = 0; cc < 8; ++cc)
    ag[cc] = mfma16bf16(__builtin_bit_cast(bf16x4, af[cc]), ind, zero4);

  if (n < nRuns) {
    unsigned short* basep = agg + (size_t)rowdst * 128;
#pragma unroll
    for (int cc = 0; cc < 8; ++cc) {
      int colb = cc * 16 + 4 * q;
      unsigned int u0 = pack2bf(ag[cc][0], ag[cc][1]);
      unsigned int u1 = pack2bf(ag[cc][2], ag[cc][3]);
      asm volatile("global_atomic_pk_add_bf16 %0, %1, off" :: "v"(basep + colb), "v"(u0) : "memory");
      asm volatile("global_atomic_pk_add_bf16 %0, %1, off" :: "v"(basep + colb + 2), "v"(u1) : "memory");
    }
  }
  asm volatile("s_waitcnt vmcnt(0)" ::: "memory");   // drain untracked asm atomics
}

// Node kernel (transposed, 512 threads): 64 nodes/block, 8 waves.
__global__ void __launch_bounds__(512, 6) node_kernel(
    const float* __restrict__ h, const short* __restrict__ agg,
    const short* __restrict__ N1f, const short* __restrict__ N2f,
    const float* __restrict__ nb1, const float* __restrict__ nb2,
    float* __restrict__ out) {
  __shared__ __align__(16) short Smem[16896];   // Z[64][264] overlaid by M1[64][136]
  const int tid = threadIdx.x;
  const int n0 = blockIdx.x * 64;
#pragma unroll
  for (int i = 0; i < 4; ++i) {
    int id = i * 512 + tid;
    int r = id >> 5, ch = id & 31;
    int rg = n0 + r;
    if (rg >= N_NODES) rg = N_NODES - 1;
    if (ch < 16) {
      const float* hp = h + (size_t)rg * 128 + ch * 8;
      float4 a = *(const float4*)hp;
      float4 b = *(const float4*)(hp + 4);
      uint4 sv;
      sv.x = pack2bf(a.x, a.y);
      sv.y = pack2bf(a.z, a.w);
      sv.z = pack2bf(b.x, b.y);
      sv.w = pack2bf(b.z, b.w);
      *(uint4*)(Smem + r * 264 + ch * 8) = sv;
    } else {
      *(uint4*)(Smem + r * 264 + ch * 8) =
          *(const uint4*)(agg + (size_t)rg * 128 + (ch - 16) * 8);
    }
  }
  __syncthreads();
  const int w = tid >> 6, lane = tid & 63, q = lane >> 4, n = lane & 15;
  const int et = w & 3, cg = w >> 2;
  const int erow = et * 16 + n;

  floatx4 acc[4];
#pragma unroll
  for (int cc = 0; cc < 4; ++cc) acc[cc] = (floatx4){0.f, 0.f, 0.f, 0.f};
  {
    const short* Brow = Smem + erow * 264 + q * 8;
    const short8* A = (const short8*)N1f;
#pragma unroll
    for (int kt = 0; kt < 8; ++kt) {
      short8 b = *(const short8*)(Brow + kt * 32);
#pragma unroll
      for (int cc = 0; cc < 4; ++cc) {
        short8 a = A[kt * 512 + (cg * 4 + cc) * 64 + lane];
        acc[cc] = __builtin_amdgcn_mfma_f32_16x16x32_bf16(a, b, acc[cc], 0, 0, 0);
      }
    }
  }
  unsigned int m1p[4][2];
#pragma unroll
  for (int cc = 0; cc < 4; ++cc) {
    int ct = cg * 4 + cc;
    const float4 b1 = *(const float4*)(nb1 + ct * 16 + 4 * q);
    m1p[cc][0] = pack2bf(fsilu(acc[cc][0] + b1.x), fsilu(acc[cc][1] + b1.y));
    m1p[cc][1] = pack2bf(fsilu(acc[cc][2] + b1.z), fsilu(acc[cc][3] + b1.w));
  }
  __syncthreads();
#pragma unroll
  for (int cc = 0; cc < 4; ++cc) {
    int ct = cg * 4 + cc;
    *(uint2*)(Smem + erow * 136 + ct * 16 + 4 * q) = *(uint2*)m1p[cc];
  }
  __syncthreads();

  floatx4 acc2[4];
#pragma unroll
  for (int cc = 0; cc < 4; ++cc) acc2[cc] = (floatx4){0.f, 0.f, 0.f, 0.f};
  {
    const short* Brow = Smem + erow * 136 + q * 8;
    const short8* A = (const short8*)N2f;
#pragma unroll
    for (int kt = 0; kt < 4; ++kt) {
      short8 b = *(const short8*)(Brow + kt * 32);
#pragma unroll
      for (int cc = 0; cc < 4; ++cc) {
        short8 a = A[kt * 512 + (cg * 4 + cc) * 64 + lane];
        acc2[cc] = __builtin_amdgcn_mfma_f32_16x16x32_bf16(a, b, acc2[cc], 0, 0, 0);
      }
    }
  }
  const int node = n0 + erow;
  if (node < N_NODES) {
#pragma unroll
    for (int cc = 0; cc < 4; ++cc) {
      int col = (cg * 4 + cc) * 16 + 4 * q;
      const float4 b2 = *(const float4*)(nb2 + col);
      const float4 hr = *(const float4*)(h + (size_t)node * 128 + col);
      float4 o;
      o.x = acc2[cc][0] + b2.x + hr.x;
      o.y = acc2[cc][1] + b2.y + hr.y;
      o.z = acc2[cc][2] + b2.z + hr.z;
      o.w = acc2[cc][3] + b2.w + hr.w;
      *(float4*)(out + (size_t)node * 128 + col) = o;
    }
  }
}

extern "C" void kernel_launch(void* const* d_in, const int* in_sizes, int n_in,
                              void* d_out, int out_size, void* d_ws, size_t ws_size,
                              hipStream_t stream) {
  (void)in_sizes; (void)n_in; (void)out_size; (void)ws_size;
  const float* h   = (const float*)d_in[0];
  const int*   idx = (const int*)d_in[1];
  const float* eW1 = (const float*)d_in[2];
  const float* eb1 = (const float*)d_in[3];
  const float* eW2 = (const float*)d_in[4];
  const float* eb2 = (const float*)d_in[5];
  const float* aW  = (const float*)d_in[6];
  const float* ab  = (const float*)d_in[7];
  const float* nW1 = (const float*)d_in[8];
  const float* nb1 = (const float*)d_in[9];
  const float* nW2 = (const float*)d_in[10];
  const float* nb2 = (const float*)d_in[11];
  float* out = (float*)d_out;

  // ws layout
  char* wp = (char*)d_ws;
  unsigned short* agg = (unsigned short*)wp;  wp += (size_t)N_NODES * 128 * 2;  // 12.8 MB
  short* Rb  = (short*)wp;                    wp += (size_t)N_NODES * 128 * 2;  // 12.8 MB
  short* Sb  = (short*)wp;                    wp += (size_t)N_NODES * 128 * 2;  // 12.8 MB
  short* W1f = (short*)wp;                    wp += 32768 * 2;
  short* W2f = (short*)wp;                    wp += 16384 * 2;
  short* N1f = (short*)wp;                    wp += 32768 * 2;
  short* N2f = (short*)wp;                    wp += 16384 * 2;
  int* cnt  = (int*)wp;                       wp += N_NODES * 4;
  int* ctmp = (int*)wp;                       wp += N_NODES * 4;
  int* rank = (int*)wp;                       wp += (size_t)N_EDGES * 4;
  int2* sedge = (int2*)wp;                    wp += (size_t)N_EDGES * 8;
  int* bsum = (int*)wp;                       wp += 128 * 4;
  int* boff = (int*)wp;                       wp += 128 * 4;

  hipMemsetAsync(agg, 0, (size_t)N_NODES * 128 * 2, stream);
  hipMemsetAsync(cnt, 0, N_NODES * 4, stream);
  prep_weights<<<48, 256, 0, stream>>>(eW1, eW2, nW1, nW2, W1f, W2f, N1f, N2f);
  prep_hR<<<(N_NODES + 63) / 64, 512, 0, stream>>>(h, W1f, eb1, Rb, Sb);
  hist_kernel<<<N_EDGES / 256, 256, 0, stream>>>(idx, cnt, rank);
  scan1<<<98, 512, 0, stream>>>(cnt, bsum);
  scan2<<<1, 128, 0, stream>>>(bsum, boff);
  scan3<<<98, 512, 0, stream>>>(cnt, boff, ctmp);
  place_kernel<<<N_EDGES / 256, 256, 0, stream>>>(idx, ctmp, rank, sedge);
  edge_kernel<<<N_EDGES / 128, 512, 0, stream>>>(Rb, Sb, sedge, W2f,
                                                 eb2, aW, ab, agg);
  node_kernel<<<(N_NODES + 63) / 64, 512, 0, stream>>>(h, (const short*)agg,
                                                       N1f, N2f, nb1, nb2, out);
}

// Round 13
// 328.799 us; speedup vs baseline: 1.2481x; 1.0911x over previous
//
#include <hip/hip_runtime.h>

#define N_NODES 50000
#define N_EDGES 800000

typedef __attribute__((ext_vector_type(8))) short short8;
typedef __attribute__((ext_vector_type(4))) short bf16x4;
typedef __attribute__((ext_vector_type(4))) float floatx4;
typedef __attribute__((ext_vector_type(2))) __bf16 bfv2;

__device__ __forceinline__ short f2bf(float f) {
  unsigned int u = __builtin_bit_cast(unsigned int, f);
  unsigned int r = (u + 0x7FFFu + ((u >> 16) & 1u)) >> 16;
  return (short)r;
}
// pack two f32 -> packed bf16 dword via compiler casts (RNE); clang fuses the
// fptrunc pair into the packed HW convert on gfx950 and keeps sched freedom.
__device__ __forceinline__ unsigned int pack2bf(float a, float b) {
  bfv2 v;
  v.x = (__bf16)a;
  v.y = (__bf16)b;
  return __builtin_bit_cast(unsigned int, v);
}
__device__ __forceinline__ float bflo2f(unsigned int u) {
  return __builtin_bit_cast(float, u << 16);
}
__device__ __forceinline__ float bfhi2f(unsigned int u) {
  return __builtin_bit_cast(float, u & 0xFFFF0000u);
}
__device__ __forceinline__ float fsilu(float v) {
  float e = __builtin_amdgcn_exp2f(v * -1.442695041f);
  return v * __builtin_amdgcn_rcpf(1.f + e);
}

// K=16 bf16 MFMA (for the segmented-reduce aggregation)
__device__ __forceinline__ floatx4 mfma16bf16(bf16x4 a, bf16x4 b, floatx4 c) {
#if __has_builtin(__builtin_amdgcn_mfma_f32_16x16x16bf16_1k)
  return __builtin_amdgcn_mfma_f32_16x16x16bf16_1k(a, b, c, 0, 0, 0);
#elif __has_builtin(__builtin_amdgcn_mfma_f32_16x16x16_bf16)
  return __builtin_amdgcn_mfma_f32_16x16x16_bf16(a, b, c, 0, 0, 0);
#else
  floatx4 d;
  asm volatile("v_mfma_f32_16x16x16_bf16 %0, %1, %2, %3"
               : "=&v"(d) : "v"(a), "v"(b), "v"(c));
  return d;
#endif
}

// f32 weights [K,128] -> bf16 MFMA frag order (A-frag of W^T == B-frag of W)
__global__ void prep_weights(const float* __restrict__ eW1, const float* __restrict__ eW2,
                             const float* __restrict__ nW1, const float* __restrict__ nW2,
                             short* __restrict__ W1f, short* __restrict__ W2f,
                             short* __restrict__ N1f, short* __restrict__ N2f) {
  int id = blockIdx.x * 256 + threadIdx.x;   // 0..12287
  const float* src; short* dst; int ch;
  if (id < 4096)       { src = eW1; dst = W1f; ch = id; }
  else if (id < 6144)  { src = eW2; dst = W2f; ch = id - 4096; }
  else if (id < 10240) { src = nW1; dst = N1f; ch = id - 6144; }
  else                 { src = nW2; dst = N2f; ch = id - 10240; }
  int kt = ch >> 9;
  int c  = (ch >> 6) & 7;
  int l  = ch & 63;
  int q = l >> 4, n = l & 15;
  int k0 = kt * 32 + q * 8;
  int col = c * 16 + n;
  short tmp[8];
#pragma unroll
  for (int j = 0; j < 8; ++j) tmp[j] = f2bf(src[(k0 + j) * 128 + col]);
#pragma unroll
  for (int j = 0; j < 8; ++j) dst[ch * 8 + j] = tmp[j];
}

// Per-node layer-1 split: R' = h @ eW1_top + eb1,  S = h @ eW1_bot (both bf16).
// Transposed GEMM, 64 nodes/block, 512 threads.
__global__ void __launch_bounds__(512, 6) prep_hR(
    const float* __restrict__ h, const short* __restrict__ W1f,
    const float* __restrict__ eb1,
    short* __restrict__ Rb, short* __restrict__ Sb) {
  __shared__ __align__(16) short Z[64 * 136];
  const int tid = threadIdx.x;
  const int n0 = blockIdx.x * 64;
#pragma unroll
  for (int i = 0; i < 4; ++i) {
    int id = i * 512 + tid;
    int r = id >> 5, cq = id & 31;
    int rg = n0 + r; if (rg >= N_NODES) rg = N_NODES - 1;
    float4 v = *(const float4*)(h + (size_t)rg * 128 + cq * 4);
    uint2 s;
    s.x = pack2bf(v.x, v.y);
    s.y = pack2bf(v.z, v.w);
    *(uint2*)(Z + r * 136 + cq * 4) = s;
  }
  __syncthreads();
  const int w = tid >> 6, lane = tid & 63, q = lane >> 4, n = lane & 15;
  const int et = w & 3, cg = w >> 2;
  const int erow = et * 16 + n;
  floatx4 accR[4], accS[4];
#pragma unroll
  for (int cc = 0; cc < 4; ++cc) {
    accR[cc] = (floatx4){0.f, 0.f, 0.f, 0.f};
    accS[cc] = (floatx4){0.f, 0.f, 0.f, 0.f};
  }
  const short* Brow = Z + erow * 136 + q * 8;
  const short8* A = (const short8*)W1f;
#pragma unroll
  for (int kt = 0; kt < 4; ++kt) {
    short8 b = *(const short8*)(Brow + kt * 32);
#pragma unroll
    for (int cc = 0; cc < 4; ++cc) {
      short8 aT = A[kt * 512 + (cg * 4 + cc) * 64 + lane];          // top half
      accR[cc] = __builtin_amdgcn_mfma_f32_16x16x32_bf16(aT, b, accR[cc], 0, 0, 0);
      short8 aB = A[(kt + 4) * 512 + (cg * 4 + cc) * 64 + lane];    // bottom half
      accS[cc] = __builtin_amdgcn_mfma_f32_16x16x32_bf16(aB, b, accS[cc], 0, 0, 0);
    }
  }
  const int node = n0 + erow;
  if (node < N_NODES) {
#pragma unroll
    for (int cc = 0; cc < 4; ++cc) {
      int col = (cg * 4 + cc) * 16 + 4 * q;
      const float4 b1 = *(const float4*)(eb1 + col);
      uint2 ur, us;
      ur.x = pack2bf(accR[cc][0] + b1.x, accR[cc][1] + b1.y);
      ur.y = pack2bf(accR[cc][2] + b1.z, accR[cc][3] + b1.w);
      us.x = pack2bf(accS[cc][0], accS[cc][1]);
      us.y = pack2bf(accS[cc][2], accS[cc][3]);
      *(uint2*)(Rb + (size_t)node * 128 + col) = ur;
      *(uint2*)(Sb + (size_t)node * 128 + col) = us;
    }
  }
}

// ---- CSR build: histogram of destination rows; atomic return = edge's rank
__global__ void hist_kernel(const int* __restrict__ idx, int* __restrict__ cnt,
                            int* __restrict__ rank) {
  int gid = blockIdx.x * 256 + threadIdx.x;
  rank[gid] = atomicAdd(&cnt[idx[gid]], 1);
}

// two-level exclusive scan of cnt[50000] -> ctmp
__global__ void scan1(const int* __restrict__ cnt, int* __restrict__ bsum) {
  const int t = threadIdx.x;
  int i = blockIdx.x * 512 + t;
  int v = (i < N_NODES) ? cnt[i] : 0;
#pragma unroll
  for (int o = 1; o < 64; o <<= 1) v += __shfl_xor(v, o, 64);
  __shared__ int ws_[8];
  if ((t & 63) == 0) ws_[t >> 6] = v;
  __syncthreads();
  if (t == 0) {
    int s = 0;
#pragma unroll
    for (int k = 0; k < 8; ++k) s += ws_[k];
    bsum[blockIdx.x] = s;
  }
}

__global__ void scan2(const int* __restrict__ bsum, int* __restrict__ boff) {
  const int t = threadIdx.x;   // 128 threads
  int v = (t < 98) ? bsum[t] : 0;
  int incl = v;
  const int lane = t & 63;
#pragma unroll
  for (int o = 1; o < 64; o <<= 1) {
    int tmp = __shfl_up(incl, o, 64);
    if (lane >= o) incl += tmp;
  }
  __shared__ int s0;
  if (t == 63) s0 = incl;
  __syncthreads();
  if (t >= 64) incl += s0;
  boff[t] = incl - v;
}

__global__ void scan3(const int* __restrict__ cnt, const int* __restrict__ boff,
                      int* __restrict__ ctmp) {
  const int t = threadIdx.x;
  const int i = blockIdx.x * 512 + t;
  int v = (i < N_NODES) ? cnt[i] : 0;
  int incl = v;
  const int lane = t & 63;
#pragma unroll
  for (int o = 1; o < 64; o <<= 1) {
    int tmp = __shfl_up(incl, o, 64);
    if (lane >= o) incl += tmp;
  }
  __shared__ int wsum[8];
  if (lane == 63) wsum[t >> 6] = incl;
  __syncthreads();
  if (t == 0) {
    int run = 0;
#pragma unroll
    for (int k = 0; k < 8; ++k) { int x = wsum[k]; wsum[k] = run; run += x; }
  }
  __syncthreads();
  if (i < N_NODES) ctmp[i] = incl - v + wsum[t >> 6] + boff[blockIdx.x];
}

// place edges into sorted order: p = row_base + precomputed rank (NO atomics)
__global__ void place_kernel(const int* __restrict__ idx, const int* __restrict__ ctmp,
                             const int* __restrict__ rank, int2* __restrict__ sedge) {
  int gid = blockIdx.x * 256 + threadIdx.x;
  int r = idx[gid];
  int c = idx[N_EDGES + gid];
  int p = ctmp[r] + rank[gid];
  sedge[p] = make_int2(r, c);
}

// Edge kernel: wave-autonomous, ZERO barriers, 256 threads = 4 independent
// waves, one 16-edge sorted tile per wave (proven best structure, rounds 4/9).
// launch_bounds (256,4): give the allocator ~64 VGPR of headroom for gather/
// unpack ILP — round 12 showed perf tracks per-wave register-backed ILP
// (VGPR 36 squeeze -> issue rate collapse), NOT occupancy. Rounds 6/8/11:
// multi-tile-per-wave live state spills to scratch -> FETCH/WRITE blowup.
// Lane (q,n):
//   layer-1: m1[edge n][32kt+8q+j] = silu(R[row_n]+S[col_n]) into A-frags.
//   layer-2: D[edge 4q+j][ch ct*16+n] via 32 MFMAs (a=M1 frag, b=W2f frag).
//   att: dot over 128 ch completes with in-wave width-16 shfl_xor reduce.
//   agg: 16x16x16 MFMA, indicator B[k=edge][col=run]=att*(rid==run);
//        lane(q,n) = run n, channels ct*16+4q..+3 -> L2-side pk asm atomics.
__global__ void __launch_bounds__(256, 4) edge_kernel(
    const short* __restrict__ Rb, const short* __restrict__ Sb,
    const int2* __restrict__ sedge, const short* __restrict__ W2f,
    const float* __restrict__ eb2, const float* __restrict__ aW,
    const float* __restrict__ ab, unsigned short* __restrict__ agg) {
  __shared__ int runrowS[64];     // 4 waves * 16 runs
  const int tid = threadIdx.x;
  const int w = tid >> 6, lane = tid & 63, q = lane >> 4, n = lane & 15;
  const int e16 = blockIdx.x * 64 + w * 16;
  const int2 ed = sedge[e16 + n];
  const int myrow = ed.x;

  // ---- layer 1: m1 = silu(R'[row]+S[col]) straight into A-frags
  const short* Rrow = Rb + (size_t)myrow * 128 + q * 8;
  const short* Srow = Sb + (size_t)ed.y * 128 + q * 8;
  short8 a[4];
#pragma unroll
  for (int kt = 0; kt < 4; ++kt) {
    uint4 ur = *(const uint4*)(Rrow + kt * 32);
    uint4 us = *(const uint4*)(Srow + kt * 32);
    float v0 = bflo2f(ur.x) + bflo2f(us.x);
    float v1 = bfhi2f(ur.x) + bfhi2f(us.x);
    float v2 = bflo2f(ur.y) + bflo2f(us.y);
    float v3 = bfhi2f(ur.y) + bfhi2f(us.y);
    float v4 = bflo2f(ur.z) + bflo2f(us.z);
    float v5 = bfhi2f(ur.z) + bfhi2f(us.z);
    float v6 = bflo2f(ur.w) + bflo2f(us.w);
    float v7 = bfhi2f(ur.w) + bfhi2f(us.w);
    uint4 pa;
    pa.x = pack2bf(fsilu(v0), fsilu(v1));
    pa.y = pack2bf(fsilu(v2), fsilu(v3));
    pa.z = pack2bf(fsilu(v4), fsilu(v5));
    pa.w = pack2bf(fsilu(v6), fsilu(v7));
    a[kt] = __builtin_bit_cast(short8, pa);
  }

  // ---- layer 2: D[edge, ch] = M1 @ W2 over all 8 channel tiles
  floatx4 acc2[8];
#pragma unroll
  for (int cc = 0; cc < 8; ++cc) acc2[cc] = (floatx4){0.f, 0.f, 0.f, 0.f};
  {
    const short8* B = (const short8*)W2f;
#pragma unroll
    for (int kt = 0; kt < 4; ++kt) {
#pragma unroll
      for (int cc = 0; cc < 8; ++cc) {
        short8 b = B[kt * 512 + cc * 64 + lane];
        acc2[cc] = __builtin_amdgcn_mfma_f32_16x16x32_bf16(a[kt], b, acc2[cc], 0, 0, 0);
      }
    }
  }

  // ---- bias + silu + att partial dot; pack sil as A-frags (P^T) for agg MFMA
  float p0 = 0.f, p1 = 0.f, p2 = 0.f, p3 = 0.f;
  uint2 af[8];
#pragma unroll
  for (int cc = 0; cc < 8; ++cc) {
    float bia = eb2[cc * 16 + n];
    float awv = aW[cc * 16 + n];
    float v0 = fsilu(acc2[cc][0] + bia);
    float v1 = fsilu(acc2[cc][1] + bia);
    float v2 = fsilu(acc2[cc][2] + bia);
    float v3 = fsilu(acc2[cc][3] + bia);
    p0 += v0 * awv; p1 += v1 * awv; p2 += v2 * awv; p3 += v3 * awv;
    af[cc].x = pack2bf(v0, v1);
    af[cc].y = pack2bf(v2, v3);
  }
  // complete the att dot across the 16 channel lanes (n) of this q-group
#pragma unroll
  for (int d = 1; d < 16; d <<= 1) {
    p0 += __shfl_xor(p0, d, 16);
    p1 += __shfl_xor(p1, d, 16);
    p2 += __shfl_xor(p2, d, 16);
    p3 += __shfl_xor(p3, d, 16);
  }

  // ---- run/head machinery (all intra-wave; rows live in registers)
  int rprev = __shfl_up(myrow, 1, 16);
  bool head = (n == 0) || (myrow != rprev);
  unsigned long long bal = __ballot(head);
  unsigned int mask16 = (unsigned int)(bal >> (q * 16)) & 0xFFFFu;
  int nRuns = __popc(mask16);
  if (head && q == 0) {
    int ridn = __popc(mask16 & ((2u << n) - 1u)) - 1;
    runrowS[w * 16 + ridn] = myrow;
  }
  asm volatile("s_waitcnt lgkmcnt(0)" ::: "memory");   // same-wave LDS RAW
  __builtin_amdgcn_sched_barrier(0);
  int rowdst = runrowS[w * 16 + n];                    // row of run n (if n<nRuns)
  int rid4[4];
#pragma unroll
  for (int j = 0; j < 4; ++j)
    rid4[j] = __popc(mask16 & ((2u << (4 * q + j)) - 1u)) - 1;

  // ---- att per edge 4q+j; indicator B-frag with att folded in
  const float ab0 = ab[0];
  float att[4];
  {
    float pv[4] = {p0, p1, p2, p3};
#pragma unroll
    for (int j = 0; j < 4; ++j) {
      float s = pv[j] + ab0;
      att[j] = 0.01f * __builtin_amdgcn_rcpf(1.f + __builtin_amdgcn_exp2f(-1.442695041f * s));
    }
  }
  uint2 iu;
  iu.x = pack2bf(rid4[0] == n ? att[0] : 0.f, rid4[1] == n ? att[1] : 0.f);
  iu.y = pack2bf(rid4[2] == n ? att[2] : 0.f, rid4[3] == n ? att[3] : 0.f);
  bf16x4 ind = __builtin_bit_cast(bf16x4, iu);

  // ---- aggregation MFMAs: ag[cc] = P_cc^T * Ind
  const floatx4 zero4 = (floatx4){0.f, 0.f, 0.f, 0.f};
  floatx4 ag[8];
#pragma unroll
  for (int cc = 0; cc < 8; ++cc)
    ag[cc] = mfma16bf16(__builtin_bit_cast(bf16x4, af[cc]), ind, zero4);

  if (n < nRuns) {
    unsigned short* basep = agg + (size_t)rowdst * 128;
#pragma unroll
    for (int cc = 0; cc < 8; ++cc) {
      int colb = cc * 16 + 4 * q;
      unsigned int u0 = pack2bf(ag[cc][0], ag[cc][1]);
      unsigned int u1 = pack2bf(ag[cc][2], ag[cc][3]);
      asm volatile("global_atomic_pk_add_bf16 %0, %1, off" :: "v"(basep + colb), "v"(u0) : "memory");
      asm volatile("global_atomic_pk_add_bf16 %0, %1, off" :: "v"(basep + colb + 2), "v"(u1) : "memory");
    }
  }
  asm volatile("s_waitcnt vmcnt(0)" ::: "memory");   // drain untracked asm atomics
}

// Node kernel (transposed, 512 threads): 64 nodes/block, 8 waves.
__global__ void __launch_bounds__(512, 6) node_kernel(
    const float* __restrict__ h, const short* __restrict__ agg,
    const short* __restrict__ N1f, const short* __restrict__ N2f,
    const float* __restrict__ nb1, const float* __restrict__ nb2,
    float* __restrict__ out) {
  __shared__ __align__(16) short Smem[16896];   // Z[64][264] overlaid by M1[64][136]
  const int tid = threadIdx.x;
  const int n0 = blockIdx.x * 64;
#pragma unroll
  for (int i = 0; i < 4; ++i) {
    int id = i * 512 + tid;
    int r = id >> 5, ch = id & 31;
    int rg = n0 + r;
    if (rg >= N_NODES) rg = N_NODES - 1;
    if (ch < 16) {
      const float* hp = h + (size_t)rg * 128 + ch * 8;
      float4 a = *(const float4*)hp;
      float4 b = *(const float4*)(hp + 4);
      uint4 sv;
      sv.x = pack2bf(a.x, a.y);
      sv.y = pack2bf(a.z, a.w);
      sv.z = pack2bf(b.x, b.y);
      sv.w = pack2bf(b.z, b.w);
      *(uint4*)(Smem + r * 264 + ch * 8) = sv;
    } else {
      *(uint4*)(Smem + r * 264 + ch * 8) =
          *(const uint4*)(agg + (size_t)rg * 128 + (ch - 16) * 8);
    }
  }
  __syncthreads();
  const int w = tid >> 6, lane = tid & 63, q = lane >> 4, n = lane & 15;
  const int et = w & 3, cg = w >> 2;
  const int erow = et * 16 + n;

  floatx4 acc[4];
#pragma unroll
  for (int cc = 0; cc < 4; ++cc) acc[cc] = (floatx4){0.f, 0.f, 0.f, 0.f};
  {
    const short* Brow = Smem + erow * 264 + q * 8;
    const short8* A = (const short8*)N1f;
#pragma unroll
    for (int kt = 0; kt < 8; ++kt) {
      short8 b = *(const short8*)(Brow + kt * 32);
#pragma unroll
      for (int cc = 0; cc < 4; ++cc) {
        short8 a = A[kt * 512 + (cg * 4 + cc) * 64 + lane];
        acc[cc] = __builtin_amdgcn_mfma_f32_16x16x32_bf16(a, b, acc[cc], 0, 0, 0);
      }
    }
  }
  unsigned int m1p[4][2];
#pragma unroll
  for (int cc = 0; cc < 4; ++cc) {
    int ct = cg * 4 + cc;
    const float4 b1 = *(const float4*)(nb1 + ct * 16 + 4 * q);
    m1p[cc][0] = pack2bf(fsilu(acc[cc][0] + b1.x), fsilu(acc[cc][1] + b1.y));
    m1p[cc][1] = pack2bf(fsilu(acc[cc][2] + b1.z), fsilu(acc[cc][3] + b1.w));
  }
  __syncthreads();
#pragma unroll
  for (int cc = 0; cc < 4; ++cc) {
    int ct = cg * 4 + cc;
    *(uint2*)(Smem + erow * 136 + ct * 16 + 4 * q) = *(uint2*)m1p[cc];
  }
  __syncthreads();

  floatx4 acc2[4];
#pragma unroll
  for (int cc = 0; cc < 4; ++cc) acc2[cc] = (floatx4){0.f, 0.f, 0.f, 0.f};
  {
    const short* Brow = Smem + erow * 136 + q * 8;
    const short8* A = (const short8*)N2f;
#pragma unroll
    for (int kt = 0; kt < 4; ++kt) {
      short8 b = *(const short8*)(Brow + kt * 32);
#pragma unroll
      for (int cc = 0; cc < 4; ++cc) {
        short8 a = A[kt * 512 + (cg * 4 + cc) * 64 + lane];
        acc2[cc] = __builtin_amdgcn_mfma_f32_16x16x32_bf16(a, b, acc2[cc], 0, 0, 0);
      }
    }
  }
  const int node = n0 + erow;
  if (node < N_NODES) {
#pragma unroll
    for (int cc = 0; cc < 4; ++cc) {
      int col = (cg * 4 + cc) * 16 + 4 * q;
      const float4 b2 = *(const float4*)(nb2 + col);
      const float4 hr = *(const float4*)(h + (size_t)node * 128 + col);
      float4 o;
      o.x = acc2[cc][0] + b2.x + hr.x;
      o.y = acc2[cc][1] + b2.y + hr.y;
      o.z = acc2[cc][2] + b2.z + hr.z;
      o.w = acc2[cc][3] + b2.w + hr.w;
      *(float4*)(out + (size_t)node * 128 + col) = o;
    }
  }
}

extern "C" void kernel_launch(void* const* d_in, const int* in_sizes, int n_in,
                              void* d_out, int out_size, void* d_ws, size_t ws_size,
                              hipStream_t stream) {
  (void)in_sizes; (void)n_in; (void)out_size; (void)ws_size;
  const float* h   = (const float*)d_in[0];
  const int*   idx = (const int*)d_in[1];
  const float* eW1 = (const float*)d_in[2];
  const float* eb1 = (const float*)d_in[3];
  const float* eW2 = (const float*)d_in[4];
  const float* eb2 = (const float*)d_in[5];
  const float* aW  = (const float*)d_in[6];
  const float* ab  = (const float*)d_in[7];
  const float* nW1 = (const float*)d_in[8];
  const float* nb1 = (const float*)d_in[9];
  const float* nW2 = (const float*)d_in[10];
  const float* nb2 = (const float*)d_in[11];
  float* out = (float*)d_out;

  // ws layout
  char* wp = (char*)d_ws;
  unsigned short* agg = (unsigned short*)wp;  wp += (size_t)N_NODES * 128 * 2;  // 12.8 MB
  short* Rb  = (short*)wp;                    wp += (size_t)N_NODES * 128 * 2;  // 12.8 MB
  short* Sb  = (short*)wp;                    wp += (size_t)N_NODES * 128 * 2;  // 12.8 MB
  short* W1f = (short*)wp;                    wp += 32768 * 2;
  short* W2f = (short*)wp;                    wp += 16384 * 2;
  short* N1f = (short*)wp;                    wp += 32768 * 2;
  short* N2f = (short*)wp;                    wp += 16384 * 2;
  int* cnt  = (int*)wp;                       wp += N_NODES * 4;
  int* ctmp = (int*)wp;                       wp += N_NODES * 4;
  int* rank = (int*)wp;                       wp += (size_t)N_EDGES * 4;
  int2* sedge = (int2*)wp;                    wp += (size_t)N_EDGES * 8;
  int* bsum = (int*)wp;                       wp += 128 * 4;
  int* boff = (int*)wp;                       wp += 128 * 4;

  hipMemsetAsync(agg, 0, (size_t)N_NODES * 128 * 2, stream);
  hipMemsetAsync(cnt, 0, N_NODES * 4, stream);
  prep_weights<<<48, 256, 0, stream>>>(eW1, eW2, nW1, nW2, W1f, W2f, N1f, N2f);
  prep_hR<<<(N_NODES + 63) / 64, 512, 0, stream>>>(h, W1f, eb1, Rb, Sb);
  hist_kernel<<<N_EDGES / 256, 256, 0, stream>>>(idx, cnt, rank);
  scan1<<<98, 512, 0, stream>>>(cnt, bsum);
  scan2<<<1, 128, 0, stream>>>(bsum, boff);
  scan3<<<98, 512, 0, stream>>>(cnt, boff, ctmp);
  place_kernel<<<N_EDGES / 256, 256, 0, stream>>>(idx, ctmp, rank, sedge);
  edge_kernel<<<N_EDGES / 64, 256, 0, stream>>>(Rb, Sb, sedge, W2f,
                                                eb2, aW, ab, agg);
  node_kernel<<<(N_NODES + 63) / 64, 512, 0, stream>>>(h, (const short*)agg,
                                                       N1f, N2f, nb1, nb2, out);
}

// Round 14
// 321.835 us; speedup vs baseline: 1.2751x; 1.0216x over previous
//
#include <hip/hip_runtime.h>

#define N_NODES 50000
#define N_EDGES 800000

typedef __attribute__((ext_vector_type(8))) short short8;
typedef __attribute__((ext_vector_type(4))) short bf16x4;
typedef __attribute__((ext_vector_type(4))) float floatx4;
typedef __attribute__((ext_vector_type(2))) __bf16 bfv2;

__device__ __forceinline__ short f2bf(float f) {
  unsigned int u = __builtin_bit_cast(unsigned int, f);
  unsigned int r = (u + 0x7FFFu + ((u >> 16) & 1u)) >> 16;
  return (short)r;
}
// pack two f32 -> packed bf16 dword via compiler casts (RNE); clang fuses the
// fptrunc pair into the packed HW convert on gfx950 and keeps sched freedom.
__device__ __forceinline__ unsigned int pack2bf(float a, float b) {
  bfv2 v;
  v.x = (__bf16)a;
  v.y = (__bf16)b;
  return __builtin_bit_cast(unsigned int, v);
}
__device__ __forceinline__ float bflo2f(unsigned int u) {
  return __builtin_bit_cast(float, u << 16);
}
__device__ __forceinline__ float bfhi2f(unsigned int u) {
  return __builtin_bit_cast(float, u & 0xFFFF0000u);
}
__device__ __forceinline__ float fsilu(float v) {
  float e = __builtin_amdgcn_exp2f(v * -1.442695041f);
  return v * __builtin_amdgcn_rcpf(1.f + e);
}

// K=16 bf16 MFMA (for the segmented-reduce aggregation)
__device__ __forceinline__ floatx4 mfma16bf16(bf16x4 a, bf16x4 b, floatx4 c) {
#if __has_builtin(__builtin_amdgcn_mfma_f32_16x16x16bf16_1k)
  return __builtin_amdgcn_mfma_f32_16x16x16bf16_1k(a, b, c, 0, 0, 0);
#elif __has_builtin(__builtin_amdgcn_mfma_f32_16x16x16_bf16)
  return __builtin_amdgcn_mfma_f32_16x16x16_bf16(a, b, c, 0, 0, 0);
#else
  floatx4 d;
  asm volatile("v_mfma_f32_16x16x16_bf16 %0, %1, %2, %3"
               : "=&v"(d) : "v"(a), "v"(b), "v"(c));
  return d;
#endif
}

// fusedA: prep_weights (blocks 0..47) || hist (blocks 48..3172).
// Independent inputs/outputs; fusing overlaps the two start-of-frame chains.
__global__ void __launch_bounds__(256) fusedA(
    const float* __restrict__ eW1, const float* __restrict__ eW2,
    const float* __restrict__ nW1, const float* __restrict__ nW2,
    short* __restrict__ W1f, short* __restrict__ W2f,
    short* __restrict__ N1f, short* __restrict__ N2f,
    const int* __restrict__ idx, int* __restrict__ cnt,
    int* __restrict__ rank) {
  if (blockIdx.x < 48) {
    // f32 weights [K,128] -> bf16 MFMA frag order (A-frag of W^T == B-frag of W)
    int id = blockIdx.x * 256 + threadIdx.x;   // 0..12287
    const float* src; short* dst; int ch;
    if (id < 4096)       { src = eW1; dst = W1f; ch = id; }
    else if (id < 6144)  { src = eW2; dst = W2f; ch = id - 4096; }
    else if (id < 10240) { src = nW1; dst = N1f; ch = id - 6144; }
    else                 { src = nW2; dst = N2f; ch = id - 10240; }
    int kt = ch >> 9;
    int c  = (ch >> 6) & 7;
    int l  = ch & 63;
    int q = l >> 4, n = l & 15;
    int k0 = kt * 32 + q * 8;
    int col = c * 16 + n;
    short tmp[8];
#pragma unroll
    for (int j = 0; j < 8; ++j) tmp[j] = f2bf(src[(k0 + j) * 128 + col]);
#pragma unroll
    for (int j = 0; j < 8; ++j) dst[ch * 8 + j] = tmp[j];
  } else {
    // histogram of destination rows; atomic return = edge's rank
    int gid = (blockIdx.x - 48) * 256 + threadIdx.x;
    rank[gid] = atomicAdd(&cnt[idx[gid]], 1);
  }
}

// two-level exclusive scan of cnt[50000] -> ctmp
__global__ void scan1(const int* __restrict__ cnt, int* __restrict__ bsum) {
  const int t = threadIdx.x;
  int i = blockIdx.x * 512 + t;
  int v = (i < N_NODES) ? cnt[i] : 0;
#pragma unroll
  for (int o = 1; o < 64; o <<= 1) v += __shfl_xor(v, o, 64);
  __shared__ int ws_[8];
  if ((t & 63) == 0) ws_[t >> 6] = v;
  __syncthreads();
  if (t == 0) {
    int s = 0;
#pragma unroll
    for (int k = 0; k < 8; ++k) s += ws_[k];
    bsum[blockIdx.x] = s;
  }
}

__global__ void scan2(const int* __restrict__ bsum, int* __restrict__ boff) {
  const int t = threadIdx.x;   // 128 threads
  int v = (t < 98) ? bsum[t] : 0;
  int incl = v;
  const int lane = t & 63;
#pragma unroll
  for (int o = 1; o < 64; o <<= 1) {
    int tmp = __shfl_up(incl, o, 64);
    if (lane >= o) incl += tmp;
  }
  __shared__ int s0;
  if (t == 63) s0 = incl;
  __syncthreads();
  if (t >= 64) incl += s0;
  boff[t] = incl - v;
}

__global__ void scan3(const int* __restrict__ cnt, const int* __restrict__ boff,
                      int* __restrict__ ctmp) {
  const int t = threadIdx.x;
  const int i = blockIdx.x * 512 + t;
  int v = (i < N_NODES) ? cnt[i] : 0;
  int incl = v;
  const int lane = t & 63;
#pragma unroll
  for (int o = 1; o < 64; o <<= 1) {
    int tmp = __shfl_up(incl, o, 64);
    if (lane >= o) incl += tmp;
  }
  __shared__ int wsum[8];
  if (lane == 63) wsum[t >> 6] = incl;
  __syncthreads();
  if (t == 0) {
    int run = 0;
#pragma unroll
    for (int k = 0; k < 8; ++k) { int x = wsum[k]; wsum[k] = run; run += x; }
  }
  __syncthreads();
  if (i < N_NODES) ctmp[i] = incl - v + wsum[t >> 6] + boff[blockIdx.x];
}

// fusedD: prep_hR (blocks 0..781) || place (blocks 782..2344).
// prep_hR needs W1f (fusedA, done); place needs ctmp (scan3, done) + rank
// (fusedA, done). Outputs disjoint (Rb/Sb vs sedge); edge consumes both after
// this dispatch completes -> race-free overlap of the two pre-edge chains.
__global__ void __launch_bounds__(512, 6) fusedD(
    const float* __restrict__ h, const short* __restrict__ W1f,
    const float* __restrict__ eb1,
    short* __restrict__ Rb, short* __restrict__ Sb,
    const int* __restrict__ idx, const int* __restrict__ ctmp,
    const int* __restrict__ rank, int2* __restrict__ sedge) {
  __shared__ __align__(16) short Z[64 * 136];
  const int tid = threadIdx.x;
  if (blockIdx.x >= 782) {
    // ---- place: p = row_base + precomputed rank (NO atomics)
    int gid = (blockIdx.x - 782) * 512 + tid;
    if (gid < N_EDGES) {
      int r = idx[gid];
      int c = idx[N_EDGES + gid];
      int p = ctmp[r] + rank[gid];
      sedge[p] = make_int2(r, c);
    }
    return;
  }
  // ---- prep_hR: R' = h @ eW1_top + eb1,  S = h @ eW1_bot (both bf16).
  const int n0 = blockIdx.x * 64;
#pragma unroll
  for (int i = 0; i < 4; ++i) {
    int id = i * 512 + tid;
    int r = id >> 5, cq = id & 31;
    int rg = n0 + r; if (rg >= N_NODES) rg = N_NODES - 1;
    float4 v = *(const float4*)(h + (size_t)rg * 128 + cq * 4);
    uint2 s;
    s.x = pack2bf(v.x, v.y);
    s.y = pack2bf(v.z, v.w);
    *(uint2*)(Z + r * 136 + cq * 4) = s;
  }
  __syncthreads();
  const int w = tid >> 6, lane = tid & 63, q = lane >> 4, n = lane & 15;
  const int et = w & 3, cg = w >> 2;
  const int erow = et * 16 + n;
  floatx4 accR[4], accS[4];
#pragma unroll
  for (int cc = 0; cc < 4; ++cc) {
    accR[cc] = (floatx4){0.f, 0.f, 0.f, 0.f};
    accS[cc] = (floatx4){0.f, 0.f, 0.f, 0.f};
  }
  const short* Brow = Z + erow * 136 + q * 8;
  const short8* A = (const short8*)W1f;
#pragma unroll
  for (int kt = 0; kt < 4; ++kt) {
    short8 b = *(const short8*)(Brow + kt * 32);
#pragma unroll
    for (int cc = 0; cc < 4; ++cc) {
      short8 aT = A[kt * 512 + (cg * 4 + cc) * 64 + lane];          // top half
      accR[cc] = __builtin_amdgcn_mfma_f32_16x16x32_bf16(aT, b, accR[cc], 0, 0, 0);
      short8 aB = A[(kt + 4) * 512 + (cg * 4 + cc) * 64 + lane];    // bottom half
      accS[cc] = __builtin_amdgcn_mfma_f32_16x16x32_bf16(aB, b, accS[cc], 0, 0, 0);
    }
  }
  const int node = n0 + erow;
  if (node < N_NODES) {
#pragma unroll
    for (int cc = 0; cc < 4; ++cc) {
      int col = (cg * 4 + cc) * 16 + 4 * q;
      const float4 b1 = *(const float4*)(eb1 + col);
      uint2 ur, us;
      ur.x = pack2bf(accR[cc][0] + b1.x, accR[cc][1] + b1.y);
      ur.y = pack2bf(accR[cc][2] + b1.z, accR[cc][3] + b1.w);
      us.x = pack2bf(accS[cc][0], accS[cc][1]);
      us.y = pack2bf(accS[cc][2], accS[cc][3]);
      *(uint2*)(Rb + (size_t)node * 128 + col) = ur;
      *(uint2*)(Sb + (size_t)node * 128 + col) = us;
    }
  }
}

// Edge kernel: wave-autonomous, ZERO barriers, 256 threads = 4 independent
// waves, one 16-edge sorted tile per wave (measured best: rounds 4/9/13).
// Rounds 6/8/11: multi-tile-per-wave live state spills to scratch ->
// FETCH/WRITE blowup. Round 12: 512-thread TLP squeezed VGPR 48->36 and
// serialized the chain. Round 13: (256,4) neutral. This is the local optimum.
// Lane (q,n):
//   layer-1: m1[edge n][32kt+8q+j] = silu(R[row_n]+S[col_n]) into A-frags.
//   layer-2: D[edge 4q+j][ch ct*16+n] via 32 MFMAs (a=M1 frag, b=W2f frag).
//   att: dot over 128 ch completes with in-wave width-16 shfl_xor reduce.
//   agg: 16x16x16 MFMA, indicator B[k=edge][col=run]=att*(rid==run);
//        lane(q,n) = run n, channels ct*16+4q..+3 -> L2-side pk asm atomics.
__global__ void __launch_bounds__(256, 5) edge_kernel(
    const short* __restrict__ Rb, const short* __restrict__ Sb,
    const int2* __restrict__ sedge, const short* __restrict__ W2f,
    const float* __restrict__ eb2, const float* __restrict__ aW,
    const float* __restrict__ ab, unsigned short* __restrict__ agg) {
  __shared__ int runrowS[64];     // 4 waves * 16 runs
  const int tid = threadIdx.x;
  const int w = tid >> 6, lane = tid & 63, q = lane >> 4, n = lane & 15;
  const int e16 = blockIdx.x * 64 + w * 16;
  const int2 ed = sedge[e16 + n];
  const int myrow = ed.x;

  // ---- layer 1: m1 = silu(R'[row]+S[col]) straight into A-frags
  const short* Rrow = Rb + (size_t)myrow * 128 + q * 8;
  const short* Srow = Sb + (size_t)ed.y * 128 + q * 8;
  short8 a[4];
#pragma unroll
  for (int kt = 0; kt < 4; ++kt) {
    uint4 ur = *(const uint4*)(Rrow + kt * 32);
    uint4 us = *(const uint4*)(Srow + kt * 32);
    float v0 = bflo2f(ur.x) + bflo2f(us.x);
    float v1 = bfhi2f(ur.x) + bfhi2f(us.x);
    float v2 = bflo2f(ur.y) + bflo2f(us.y);
    float v3 = bfhi2f(ur.y) + bfhi2f(us.y);
    float v4 = bflo2f(ur.z) + bflo2f(us.z);
    float v5 = bfhi2f(ur.z) + bfhi2f(us.z);
    float v6 = bflo2f(ur.w) + bflo2f(us.w);
    float v7 = bfhi2f(ur.w) + bfhi2f(us.w);
    uint4 pa;
    pa.x = pack2bf(fsilu(v0), fsilu(v1));
    pa.y = pack2bf(fsilu(v2), fsilu(v3));
    pa.z = pack2bf(fsilu(v4), fsilu(v5));
    pa.w = pack2bf(fsilu(v6), fsilu(v7));
    a[kt] = __builtin_bit_cast(short8, pa);
  }

  // ---- layer 2: D[edge, ch] = M1 @ W2 over all 8 channel tiles
  floatx4 acc2[8];
#pragma unroll
  for (int cc = 0; cc < 8; ++cc) acc2[cc] = (floatx4){0.f, 0.f, 0.f, 0.f};
  {
    const short8* B = (const short8*)W2f;
#pragma unroll
    for (int kt = 0; kt < 4; ++kt) {
#pragma unroll
      for (int cc = 0; cc < 8; ++cc) {
        short8 b = B[kt * 512 + cc * 64 + lane];
        acc2[cc] = __builtin_amdgcn_mfma_f32_16x16x32_bf16(a[kt], b, acc2[cc], 0, 0, 0);
      }
    }
  }

  // ---- bias + silu + att partial dot; pack sil as A-frags (P^T) for agg MFMA
  float p0 = 0.f, p1 = 0.f, p2 = 0.f, p3 = 0.f;
  uint2 af[8];
#pragma unroll
  for (int cc = 0; cc < 8; ++cc) {
    float bia = eb2[cc * 16 + n];
    float awv = aW[cc * 16 + n];
    float v0 = fsilu(acc2[cc][0] + bia);
    float v1 = fsilu(acc2[cc][1] + bia);
    float v2 = fsilu(acc2[cc][2] + bia);
    float v3 = fsilu(acc2[cc][3] + bia);
    p0 += v0 * awv; p1 += v1 * awv; p2 += v2 * awv; p3 += v3 * awv;
    af[cc].x = pack2bf(v0, v1);
    af[cc].y = pack2bf(v2, v3);
  }
  // complete the att dot across the 16 channel lanes (n) of this q-group
#pragma unroll
  for (int d = 1; d < 16; d <<= 1) {
    p0 += __shfl_xor(p0, d, 16);
    p1 += __shfl_xor(p1, d, 16);
    p2 += __shfl_xor(p2, d, 16);
    p3 += __shfl_xor(p3, d, 16);
  }

  // ---- run/head machinery (all intra-wave; rows live in registers)
  int rprev = __shfl_up(myrow, 1, 16);
  bool head = (n == 0) || (myrow != rprev);
  unsigned long long bal = __ballot(head);
  unsigned int mask16 = (unsigned int)(bal >> (q * 16)) & 0xFFFFu;
  int nRuns = __popc(mask16);
  if (head && q == 0) {
    int ridn = __popc(mask16 & ((2u << n) - 1u)) - 1;
    runrowS[w * 16 + ridn] = myrow;
  }
  asm volatile("s_waitcnt lgkmcnt(0)" ::: "memory");   // same-wave LDS RAW
  __builtin_amdgcn_sched_barrier(0);
  int rowdst = runrowS[w * 16 + n];                    // row of run n (if n<nRuns)
  int rid4[4];
#pragma unroll
  for (int j = 0; j < 4; ++j)
    rid4[j] = __popc(mask16 & ((2u << (4 * q + j)) - 1u)) - 1;

  // ---- att per edge 4q+j; indicator B-frag with att folded in
  const float ab0 = ab[0];
  float att[4];
  {
    float pv[4] = {p0, p1, p2, p3};
#pragma unroll
    for (int j = 0; j < 4; ++j) {
      float s = pv[j] + ab0;
      att[j] = 0.01f * __builtin_amdgcn_rcpf(1.f + __builtin_amdgcn_exp2f(-1.442695041f * s));
    }
  }
  uint2 iu;
  iu.x = pack2bf(rid4[0] == n ? att[0] : 0.f, rid4[1] == n ? att[1] : 0.f);
  iu.y = pack2bf(rid4[2] == n ? att[2] : 0.f, rid4[3] == n ? att[3] : 0.f);
  bf16x4 ind = __builtin_bit_cast(bf16x4, iu);

  // ---- aggregation MFMAs: ag[cc] = P_cc^T * Ind
  const floatx4 zero4 = (floatx4){0.f, 0.f, 0.f, 0.f};
  floatx4 ag[8];
#pragma unroll
  for (int cc = 0; cc < 8; ++cc)
    ag[cc] = mfma16bf16(__builtin_bit_cast(bf16x4, af[cc]), ind, zero4);

  if (n < nRuns) {
    unsigned short* basep = agg + (size_t)rowdst * 128;
#pragma unroll
    for (int cc = 0; cc < 8; ++cc) {
      int colb = cc * 16 + 4 * q;
      unsigned int u0 = pack2bf(ag[cc][0], ag[cc][1]);
      unsigned int u1 = pack2bf(ag[cc][2], ag[cc][3]);
      asm volatile("global_atomic_pk_add_bf16 %0, %1, off" :: "v"(basep + colb), "v"(u0) : "memory");
      asm volatile("global_atomic_pk_add_bf16 %0, %1, off" :: "v"(basep + colb + 2), "v"(u1) : "memory");
    }
  }
  asm volatile("s_waitcnt vmcnt(0)" ::: "memory");   // drain untracked asm atomics
}

// Node kernel (transposed, 512 threads): 64 nodes/block, 8 waves.
__global__ void __launch_bounds__(512, 6) node_kernel(
    const float* __restrict__ h, const short* __restrict__ agg,
    const short* __restrict__ N1f, const short* __restrict__ N2f,
    const float* __restrict__ nb1, const float* __restrict__ nb2,
    float* __restrict__ out) {
  __shared__ __align__(16) short Smem[16896];   // Z[64][264] overlaid by M1[64][136]
  const int tid = threadIdx.x;
  const int n0 = blockIdx.x * 64;
#pragma unroll
  for (int i = 0; i < 4; ++i) {
    int id = i * 512 + tid;
    int r = id >> 5, ch = id & 31;
    int rg = n0 + r;
    if (rg >= N_NODES) rg = N_NODES - 1;
    if (ch < 16) {
      const float* hp = h + (size_t)rg * 128 + ch * 8;
      float4 a = *(const float4*)hp;
      float4 b = *(const float4*)(hp + 4);
      uint4 sv;
      sv.x = pack2bf(a.x, a.y);
      sv.y = pack2bf(a.z, a.w);
      sv.z = pack2bf(b.x, b.y);
      sv.w = pack2bf(b.z, b.w);
      *(uint4*)(Smem + r * 264 + ch * 8) = sv;
    } else {
      *(uint4*)(Smem + r * 264 + ch * 8) =
          *(const uint4*)(agg + (size_t)rg * 128 + (ch - 16) * 8);
    }
  }
  __syncthreads();
  const int w = tid >> 6, lane = tid & 63, q = lane >> 4, n = lane & 15;
  const int et = w & 3, cg = w >> 2;
  const int erow = et * 16 + n;

  floatx4 acc[4];
#pragma unroll
  for (int cc = 0; cc < 4; ++cc) acc[cc] = (floatx4){0.f, 0.f, 0.f, 0.f};
  {
    const short* Brow = Smem + erow * 264 + q * 8;
    const short8* A = (const short8*)N1f;
#pragma unroll
    for (int kt = 0; kt < 8; ++kt) {
      short8 b = *(const short8*)(Brow + kt * 32);
#pragma unroll
      for (int cc = 0; cc < 4; ++cc) {
        short8 a = A[kt * 512 + (cg * 4 + cc) * 64 + lane];
        acc[cc] = __builtin_amdgcn_mfma_f32_16x16x32_bf16(a, b, acc[cc], 0, 0, 0);
      }
    }
  }
  unsigned int m1p[4][2];
#pragma unroll
  for (int cc = 0; cc < 4; ++cc) {
    int ct = cg * 4 + cc;
    const float4 b1 = *(const float4*)(nb1 + ct * 16 + 4 * q);
    m1p[cc][0] = pack2bf(fsilu(acc[cc][0] + b1.x), fsilu(acc[cc][1] + b1.y));
    m1p[cc][1] = pack2bf(fsilu(acc[cc][2] + b1.z), fsilu(acc[cc][3] + b1.w));
  }
  __syncthreads();
#pragma unroll
  for (int cc = 0; cc < 4; ++cc) {
    int ct = cg * 4 + cc;
    *(uint2*)(Smem + erow * 136 + ct * 16 + 4 * q) = *(uint2*)m1p[cc];
  }
  __syncthreads();

  floatx4 acc2[4];
#pragma unroll
  for (int cc = 0; cc < 4; ++cc) acc2[cc] = (floatx4){0.f, 0.f, 0.f, 0.f};
  {
    const short* Brow = Smem + erow * 136 + q * 8;
    const short8* A = (const short8*)N2f;
#pragma unroll
    for (int kt = 0; kt < 4; ++kt) {
      short8 b = *(const short8*)(Brow + kt * 32);
#pragma unroll
      for (int cc = 0; cc < 4; ++cc) {
        short8 a = A[kt * 512 + (cg * 4 + cc) * 64 + lane];
        acc2[cc] = __builtin_amdgcn_mfma_f32_16x16x32_bf16(a, b, acc2[cc], 0, 0, 0);
      }
    }
  }
  const int node = n0 + erow;
  if (node < N_NODES) {
#pragma unroll
    for (int cc = 0; cc < 4; ++cc) {
      int col = (cg * 4 + cc) * 16 + 4 * q;
      const float4 b2 = *(const float4*)(nb2 + col);
      const float4 hr = *(const float4*)(h + (size_t)node * 128 + col);
      float4 o;
      o.x = acc2[cc][0] + b2.x + hr.x;
      o.y = acc2[cc][1] + b2.y + hr.y;
      o.z = acc2[cc][2] + b2.z + hr.z;
      o.w = acc2[cc][3] + b2.w + hr.w;
      *(float4*)(out + (size_t)node * 128 + col) = o;
    }
  }
}

extern "C" void kernel_launch(void* const* d_in, const int* in_sizes, int n_in,
                              void* d_out, int out_size, void* d_ws, size_t ws_size,
                              hipStream_t stream) {
  (void)in_sizes; (void)n_in; (void)out_size; (void)ws_size;
  const float* h   = (const float*)d_in[0];
  const int*   idx = (const int*)d_in[1];
  const float* eW1 = (const float*)d_in[2];
  const float* eb1 = (const float*)d_in[3];
  const float* eW2 = (const float*)d_in[4];
  const float* eb2 = (const float*)d_in[5];
  const float* aW  = (const float*)d_in[6];
  const float* ab  = (const float*)d_in[7];
  const float* nW1 = (const float*)d_in[8];
  const float* nb1 = (const float*)d_in[9];
  const float* nW2 = (const float*)d_in[10];
  const float* nb2 = (const float*)d_in[11];
  float* out = (float*)d_out;

  // ws layout
  char* wp = (char*)d_ws;
  unsigned short* agg = (unsigned short*)wp;  wp += (size_t)N_NODES * 128 * 2;  // 12.8 MB
  short* Rb  = (short*)wp;                    wp += (size_t)N_NODES * 128 * 2;  // 12.8 MB
  short* Sb  = (short*)wp;                    wp += (size_t)N_NODES * 128 * 2;  // 12.8 MB
  short* W1f = (short*)wp;                    wp += 32768 * 2;
  short* W2f = (short*)wp;                    wp += 16384 * 2;
  short* N1f = (short*)wp;                    wp += 32768 * 2;
  short* N2f = (short*)wp;                    wp += 16384 * 2;
  int* cnt  = (int*)wp;                       wp += N_NODES * 4;
  int* ctmp = (int*)wp;                       wp += N_NODES * 4;
  int* rank = (int*)wp;                       wp += (size_t)N_EDGES * 4;
  int2* sedge = (int2*)wp;                    wp += (size_t)N_EDGES * 8;
  int* bsum = (int*)wp;                       wp += 128 * 4;
  int* boff = (int*)wp;                       wp += 128 * 4;

  hipMemsetAsync(agg, 0, (size_t)N_NODES * 128 * 2, stream);
  hipMemsetAsync(cnt, 0, N_NODES * 4, stream);
  // fusedA: prep_weights (48 blocks) || hist (3125 blocks)
  fusedA<<<48 + N_EDGES / 256, 256, 0, stream>>>(eW1, eW2, nW1, nW2,
                                                 W1f, W2f, N1f, N2f,
                                                 idx, cnt, rank);
  scan1<<<98, 512, 0, stream>>>(cnt, bsum);
  scan2<<<1, 128, 0, stream>>>(bsum, boff);
  scan3<<<98, 512, 0, stream>>>(cnt, boff, ctmp);
  // fusedD: prep_hR (782 blocks) || place (1563 blocks)
  fusedD<<<782 + (N_EDGES + 511) / 512, 512, 0, stream>>>(h, W1f, eb1, Rb, Sb,
                                                          idx, ctmp, rank, sedge);
  edge_kernel<<<N_EDGES / 64, 256, 0, stream>>>(Rb, Sb, sedge, W2f,
                                                eb2, aW, ab, agg);
  node_kernel<<<(N_NODES + 63) / 64, 512, 0, stream>>>(h, (const short*)agg,
                                                       N1f, N2f, nb1, nb2, out);
}